// Round 2
// baseline (597.587 us; speedup 1.0000x reference)
//
#include <hip/hip_runtime.h>
#include <hip/hip_fp16.h>

// ---------------------------------------------------------------------------
// K1: C[m,j] = sum_c A[m,c]*W[j,c] + bias[j]   (M x 1024) @ (1024 x 1024)^T
// f32 in/out. Tile 64x64, BK=32, 256 threads, 4x4 micro-tile.
// ---------------------------------------------------------------------------
__global__ __launch_bounds__(256)
void proj_gemm(const float* __restrict__ A, const float* __restrict__ W,
               const float* __restrict__ bias, float* __restrict__ C) {
    __shared__ __align__(16) float As[32][68];  // [k][m]
    __shared__ __align__(16) float Ws[32][68];  // [k][j]
    const int m0 = blockIdx.y * 64, j0 = blockIdx.x * 64;
    const int t = threadIdx.x, tx = t & 15, ty = t >> 4;
    float acc[4][4] = {};
    for (int k0 = 0; k0 < 1024; k0 += 32) {
#pragma unroll
        for (int i = 0; i < 2; ++i) {
            int idx = i * 256 + t;           // 512 float4 slots
            int r = idx >> 3, c4 = idx & 7;  // row 0..63, float4 col 0..7
            float4 a = *(const float4*)&A[(size_t)(m0 + r) * 1024 + k0 + c4 * 4];
            As[c4 * 4 + 0][r] = a.x; As[c4 * 4 + 1][r] = a.y;
            As[c4 * 4 + 2][r] = a.z; As[c4 * 4 + 3][r] = a.w;
            float4 w = *(const float4*)&W[(size_t)(j0 + r) * 1024 + k0 + c4 * 4];
            Ws[c4 * 4 + 0][r] = w.x; Ws[c4 * 4 + 1][r] = w.y;
            Ws[c4 * 4 + 2][r] = w.z; Ws[c4 * 4 + 3][r] = w.w;
        }
        __syncthreads();
#pragma unroll
        for (int kk = 0; kk < 32; ++kk) {
            float4 av = *(const float4*)&As[kk][ty * 4];
            float4 bv = *(const float4*)&Ws[kk][tx * 4];
            float a[4] = {av.x, av.y, av.z, av.w};
            float b[4] = {bv.x, bv.y, bv.z, bv.w};
#pragma unroll
            for (int i = 0; i < 4; ++i)
#pragma unroll
                for (int j = 0; j < 4; ++j) acc[i][j] += a[i] * b[j];
        }
        __syncthreads();
    }
#pragma unroll
    for (int i = 0; i < 4; ++i) {
        int m = m0 + ty * 4 + i;
#pragma unroll
        for (int j = 0; j < 4; ++j) {
            int jj = j0 + tx * 4 + j;
            float v = acc[i][j];
            if (bias) v += bias[jj];
            C[(size_t)m * 1024 + jj] = v;
        }
    }
}

// ---------------------------------------------------------------------------
// K2a: ATT[n,g,pl] = (1/16) * sum_d Q[n,g*64+d] * K[p0+pl, g*64+d]   (f16 out)
// ---------------------------------------------------------------------------
__global__ __launch_bounds__(256)
void att_gemm(const float* __restrict__ Q, const float* __restrict__ Km,
              __half* __restrict__ ATT, const int* __restrict__ n1b_p,
              const int* __restrict__ n1p_p, int PT) {
    __shared__ __align__(16) float As[32][68];
    __shared__ __align__(16) float Bs[32][68];
    const int g = blockIdx.z;
    const int n0 = blockIdx.y * 64;
    const int pl0 = blockIdx.x * 64;
    const int n1b = *n1b_p, n1p = *n1p_p;
    const int hh = (n0 >= n1b) ? 1 : 0;
    const int p0 = hh ? n1p : 0;
    const int Ph = hh ? (PT - n1p) : n1p;
    if (pl0 >= Ph) return;
    const int t = threadIdx.x, tx = t & 15, ty = t >> 4;
    float acc[4][4] = {};
    for (int k0 = 0; k0 < 64; k0 += 32) {
#pragma unroll
        for (int i = 0; i < 2; ++i) {
            int idx = i * 256 + t;
            int r = idx >> 3, c4 = idx & 7;
            float4 a = *(const float4*)&Q[(size_t)(n0 + r) * 1024 + g * 64 + k0 + c4 * 4];
            As[c4 * 4 + 0][r] = a.x; As[c4 * 4 + 1][r] = a.y;
            As[c4 * 4 + 2][r] = a.z; As[c4 * 4 + 3][r] = a.w;
            int pr = pl0 + r; if (pr >= Ph) pr = Ph - 1;
            float4 b = *(const float4*)&Km[(size_t)(p0 + pr) * 1024 + g * 64 + k0 + c4 * 4];
            Bs[c4 * 4 + 0][r] = b.x; Bs[c4 * 4 + 1][r] = b.y;
            Bs[c4 * 4 + 2][r] = b.z; Bs[c4 * 4 + 3][r] = b.w;
        }
        __syncthreads();
#pragma unroll
        for (int kk = 0; kk < 32; ++kk) {
            float4 av = *(const float4*)&As[kk][ty * 4];
            float4 bv = *(const float4*)&Bs[kk][tx * 4];
            float a[4] = {av.x, av.y, av.z, av.w};
            float b[4] = {bv.x, bv.y, bv.z, bv.w};
#pragma unroll
            for (int i = 0; i < 4; ++i)
#pragma unroll
                for (int j = 0; j < 4; ++j) acc[i][j] += a[i] * b[j];
        }
        __syncthreads();
    }
#pragma unroll
    for (int i = 0; i < 4; ++i) {
        int n = n0 + ty * 4 + i;
#pragma unroll
        for (int j = 0; j < 4; ++j) {
            int pl = pl0 + tx * 4 + j;
            if (pl < Ph)
                ATT[((size_t)n * 16 + g) * 1024 + pl] = __float2half(acc[i][j] * 0.0625f);
        }
    }
}

// ---------------------------------------------------------------------------
// K2b: per-n block. Position embedding + Wg projection on the fly,
// logit = log(clamp(relu(pos_feat),1e-6)) + att, softmax over p, in-place f16.
// ---------------------------------------------------------------------------
__global__ __launch_bounds__(256)
void softmax_pos(const float* __restrict__ rois, const float* __restrict__ prois,
                 const float* __restrict__ Wg_w, const float* __restrict__ Wg_b,
                 __half* __restrict__ ATT, const int* __restrict__ n1b_p,
                 const int* __restrict__ n1p_p, int PT) {
    const int n = blockIdx.x;
    const int t = threadIdx.x;
    const int n1b = *n1b_p, n1p = *n1p_p;
    const int hh = (n >= n1b) ? 1 : 0;
    const int p0 = hh ? n1p : 0;
    const int Ph = hh ? (PT - n1p) : n1p;

    __shared__ float wg[1024];
    __shared__ float wgb[16];
    __shared__ float redm[4][16];
    __shared__ float redl[4][16];

    for (int i = t; i < 1024; i += 256) wg[i] = Wg_w[i];
    if (t < 16) wgb[t] = Wg_b[t];

    float xmin = rois[n * 5 + 1], ymin = rois[n * 5 + 2];
    float xmax = rois[n * 5 + 3], ymax = rois[n * 5 + 4];
    float bw = xmax - xmin + 1.0f, bh = ymax - ymin + 1.0f;
    float cx = 0.5f * (xmin + xmax), cy = 0.5f * (ymin + ymax);
    __syncthreads();

    const float inv_em[8] = {1.0f, 0.4216965034f, 0.1778279410f, 0.0749894209f,
                             0.0316227766f, 0.0133352143f, 0.0056234133f, 0.0023713737f};
    float logit[16][4];

#pragma unroll
    for (int it = 0; it < 4; ++it) {
        int pl = it * 256 + t;
        if (pl < Ph) {
            int p = p0 + pl;
            float pxmin = prois[p * 5 + 1], pymin = prois[p * 5 + 2];
            float pxmax = prois[p * 5 + 3], pymax = prois[p * 5 + 4];
            float pw = pxmax - pxmin + 1.0f, ph2 = pymax - pymin + 1.0f;
            float pcx = 0.5f * (pxmin + pxmax), pcy = 0.5f * (pymin + pymax);
            float pos[4];
            pos[0] = __logf(fmaxf(fabsf((cx - pcx) / bw), 0.001f));
            pos[1] = __logf(fmaxf(fabsf((cy - pcy) / bh), 0.001f));
            pos[2] = __logf(pw / bw);
            pos[3] = __logf(ph2 / bh);
            float pf[16];
#pragma unroll
            for (int g = 0; g < 16; ++g) pf[g] = wgb[g];
#pragma unroll
            for (int j = 0; j < 4; ++j) {
                float base = 100.0f * pos[j];
#pragma unroll
                for (int k = 0; k < 8; ++k) {
                    float d = base * inv_em[k];
                    float s = __sinf(d), c2 = __cosf(d);
#pragma unroll
                    for (int g = 0; g < 16; ++g)
                        pf[g] += s * wg[g * 64 + j * 16 + k] + c2 * wg[g * 64 + j * 16 + 8 + k];
                }
            }
#pragma unroll
            for (int g = 0; g < 16; ++g) {
                float aw = fmaxf(pf[g], 1e-6f);  // relu + clamp combined
                float att = __half2float(ATT[((size_t)n * 16 + g) * 1024 + pl]);
                logit[g][it] = __logf(aw) + att;
            }
        } else {
#pragma unroll
            for (int g = 0; g < 16; ++g) logit[g][it] = -1e30f;
        }
    }

    // block-wide max per g
    float mg[16];
#pragma unroll
    for (int g = 0; g < 16; ++g)
        mg[g] = fmaxf(fmaxf(logit[g][0], logit[g][1]), fmaxf(logit[g][2], logit[g][3]));
#pragma unroll
    for (int off = 32; off >= 1; off >>= 1)
#pragma unroll
        for (int g = 0; g < 16; ++g)
            mg[g] = fmaxf(mg[g], __shfl_xor(mg[g], off, 64));
    const int wv = t >> 6, ln = t & 63;
    if (ln == 0) {
#pragma unroll
        for (int g = 0; g < 16; ++g) redm[wv][g] = mg[g];
    }
    __syncthreads();
#pragma unroll
    for (int g = 0; g < 16; ++g)
        mg[g] = fmaxf(fmaxf(redm[0][g], redm[1][g]), fmaxf(redm[2][g], redm[3][g]));

    // exp + block-wide sum per g
    float lg[16];
#pragma unroll
    for (int g = 0; g < 16; ++g) lg[g] = 0.0f;
#pragma unroll
    for (int it = 0; it < 4; ++it)
#pragma unroll
        for (int g = 0; g < 16; ++g) {
            float w = __expf(logit[g][it] - mg[g]);
            logit[g][it] = w;
            lg[g] += w;
        }
#pragma unroll
    for (int off = 32; off >= 1; off >>= 1)
#pragma unroll
        for (int g = 0; g < 16; ++g)
            lg[g] += __shfl_xor(lg[g], off, 64);
    if (ln == 0) {
#pragma unroll
        for (int g = 0; g < 16; ++g) redl[wv][g] = lg[g];
    }
    __syncthreads();
#pragma unroll
    for (int g = 0; g < 16; ++g)
        lg[g] = 1.0f / (redl[0][g] + redl[1][g] + redl[2][g] + redl[3][g]);

#pragma unroll
    for (int it = 0; it < 4; ++it) {
        int pl = it * 256 + t;
        if (pl < Ph) {
#pragma unroll
            for (int g = 0; g < 16; ++g)
                ATT[((size_t)n * 16 + g) * 1024 + pl] = __float2half(logit[g][it] * lg[g]);
        }
    }
}

// ---------------------------------------------------------------------------
// K3: OUT[n, g*64+o] = sum_pl SM[n,g,pl] * PV[p0+pl, g*64+o] + conv_b[g*64+o]
// ---------------------------------------------------------------------------
__global__ __launch_bounds__(256)
void rel_gemm(const __half* __restrict__ SM, const float* __restrict__ PV,
              const float* __restrict__ conv_b, float* __restrict__ OUT,
              const int* __restrict__ n1b_p, const int* __restrict__ n1p_p, int PT) {
    __shared__ __align__(16) float As[32][68];  // [k][n]
    __shared__ __align__(16) float Bs[32][68];  // [k][o]
    const int n0 = blockIdx.x * 64;
    const int g = blockIdx.y;
    const int n1b = *n1b_p, n1p = *n1p_p;
    const int hh = (n0 >= n1b) ? 1 : 0;
    const int p0 = hh ? n1p : 0;
    const int Ph = hh ? (PT - n1p) : n1p;
    const int t = threadIdx.x, tx = t & 15, ty = t >> 4;
    float acc[4][4] = {};
    for (int k0 = 0; k0 < Ph; k0 += 32) {
        // A: 64 n-rows x 32 k of f16 = 1024 half2 slots
#pragma unroll
        for (int i = 0; i < 4; ++i) {
            int idx = i * 256 + t;
            int r = idx >> 4, c2 = idx & 15;
            __half2 h = *(const __half2*)&SM[((size_t)(n0 + r) * 16 + g) * 1024 + k0 + c2 * 2];
            As[c2 * 2 + 0][r] = __half2float(h.x);
            As[c2 * 2 + 1][r] = __half2float(h.y);
        }
        // B: 32 k-rows x 64 o of f32 = 512 float4 slots
#pragma unroll
        for (int i = 0; i < 2; ++i) {
            int idx = i * 256 + t;
            int kr = idx >> 4, o4 = idx & 15;
            float4 b = *(const float4*)&PV[(size_t)(p0 + k0 + kr) * 1024 + g * 64 + o4 * 4];
            *(float4*)&Bs[kr][o4 * 4] = b;
        }
        __syncthreads();
#pragma unroll
        for (int kk = 0; kk < 32; ++kk) {
            float4 av = *(const float4*)&As[kk][ty * 4];
            float4 bv = *(const float4*)&Bs[kk][tx * 4];
            float a[4] = {av.x, av.y, av.z, av.w};
            float b[4] = {bv.x, bv.y, bv.z, bv.w};
#pragma unroll
            for (int i = 0; i < 4; ++i)
#pragma unroll
                for (int j = 0; j < 4; ++j) acc[i][j] += a[i] * b[j];
        }
        __syncthreads();
    }
#pragma unroll
    for (int i = 0; i < 4; ++i) {
        int n = n0 + ty * 4 + i;
#pragma unroll
        for (int j = 0; j < 4; ++j) {
            int o = tx * 4 + j;
            OUT[(size_t)n * 1024 + g * 64 + o] = acc[i][j] + conv_b[g * 64 + o];
        }
    }
}

extern "C" void kernel_launch(void* const* d_in, const int* in_sizes, int n_in,
                              void* d_out, int out_size, void* d_ws, size_t ws_size,
                              hipStream_t stream) {
    const float* rois    = (const float*)d_in[0];
    const float* prois   = (const float*)d_in[1];
    const float* bfeat   = (const float*)d_in[2];
    const float* pfeat   = (const float*)d_in[3];
    const float* Wg_w    = (const float*)d_in[4];
    const float* Wg_b    = (const float*)d_in[5];
    const float* Wq_w    = (const float*)d_in[6];
    const float* Wq_b    = (const float*)d_in[7];
    const float* Wk_w    = (const float*)d_in[8];
    // d_in[9] = Wk_b
    const float* Wk_b    = (const float*)d_in[9];
    const float* conv_w  = (const float*)d_in[10];
    const float* conv_b  = (const float*)d_in[11];
    const int*   n1b     = (const int*)d_in[12];
    const int*   n1p     = (const int*)d_in[13];

    const int NT = in_sizes[2] / 1024;  // 2048 boxes
    const int PT = in_sizes[3] / 1024;  // 2048 parts

    float* Q  = (float*)d_ws;
    float* Km = Q + (size_t)NT * 1024;
    float* PV = Km + (size_t)PT * 1024;
    __half* ATT = (__half*)(PV + (size_t)PT * 1024);  // [NT][16][1024]

    dim3 blk(256);
    proj_gemm<<<dim3(16, NT / 64), blk, 0, stream>>>(bfeat, Wq_w, Wq_b, Q);
    proj_gemm<<<dim3(16, PT / 64), blk, 0, stream>>>(pfeat, Wk_w, Wk_b, Km);
    proj_gemm<<<dim3(16, PT / 64), blk, 0, stream>>>(pfeat, conv_w, nullptr, PV);
    att_gemm<<<dim3(PT / 64, NT / 64, 16), blk, 0, stream>>>(Q, Km, ATT, n1b, n1p, PT);
    softmax_pos<<<dim3(NT), blk, 0, stream>>>(rois, prois, Wg_w, Wg_b, ATT, n1b, n1p, PT);
    rel_gemm<<<dim3(NT / 64, 16), blk, 0, stream>>>(ATT, PV, conv_b, (float*)d_out, n1b, n1p, PT);
}

// Round 3
// 258.065 us; speedup vs baseline: 2.3157x; 2.3157x over previous
//
#include <hip/hip_runtime.h>

typedef unsigned short u16;
using short8  = __attribute__((ext_vector_type(8))) short;
using float4v = __attribute__((ext_vector_type(4))) float;

__device__ __forceinline__ u16 f2bf(float f) {
    union { float f; unsigned u; } v; v.f = f;
    unsigned r = (v.u + 0x7fff + ((v.u >> 16) & 1)) >> 16;
    return (u16)r;
}
__device__ __forceinline__ float bf2f(u16 h) {
    union { unsigned u; float f; } v; v.u = ((unsigned)h) << 16; return v.f;
}
__device__ __forceinline__ void dma16(const void* g, void* l) {
    __builtin_amdgcn_global_load_lds((const __attribute__((address_space(1))) void*)g,
                                     (__attribute__((address_space(3))) void*)l, 16, 0, 0);
}

// ---------------------------------------------------------------------------
// f32 -> bf16 bulk convert (n4 = count/4)
// ---------------------------------------------------------------------------
__global__ __launch_bounds__(256)
void cvt_bf16(const float* __restrict__ src, u16* __restrict__ dst, int n4) {
    int i = blockIdx.x * 256 + threadIdx.x;
    if (i < n4) {
        float4 v = ((const float4*)src)[i];
        ushort4 o;
        o.x = f2bf(v.x); o.y = f2bf(v.y); o.z = f2bf(v.z); o.w = f2bf(v.w);
        ((ushort4*)dst)[i] = o;
    }
}

// ---------------------------------------------------------------------------
// proj: C[m,j] = sum_k A[m,k]*W[j,k] (+bias). z=0: Q, z=1: K, z=2: PV->PVt.
// 128x128 tile, BK=64, 4 waves (2x2), 4x4 subtiles of 16x16x32 MFMA.
// ---------------------------------------------------------------------------
__global__ __launch_bounds__(256)
void proj_mfma(const u16* __restrict__ Ab, const u16* __restrict__ Pb,
               const u16* __restrict__ Wqb, const u16* __restrict__ Wkb,
               const u16* __restrict__ Cwb, const float* __restrict__ bq,
               const float* __restrict__ bk, u16* __restrict__ Qb,
               u16* __restrict__ Kb, u16* __restrict__ PVt, int PT) {
    __shared__ __align__(16) u16 As[128 * 64];
    __shared__ __align__(16) u16 Ws[128 * 64];
    __shared__ __align__(16) u16 Tr[128 * 130];

    const int z = blockIdx.z;
    const int m0 = blockIdx.y * 128, j0 = blockIdx.x * 128;
    const u16* A = (z == 0) ? Ab : Pb;
    const u16* W = (z == 0) ? Wqb : (z == 1 ? Wkb : Cwb);
    const int t = threadIdx.x;
    const int w = t >> 6, lane = t & 63;
    const int wm = w >> 1, wn = w & 1;
    const int lr = lane >> 3, lc = lane & 7, gch = lc ^ lr;
    const int fm = lane & 15, quad = lane >> 4;

    float4v zero4 = {0.f, 0.f, 0.f, 0.f};
    float4v acc[4][4];
#pragma unroll
    for (int i = 0; i < 4; ++i)
#pragma unroll
        for (int j = 0; j < 4; ++j) acc[i][j] = zero4;

    for (int k0 = 0; k0 < 1024; k0 += 64) {
#pragma unroll
        for (int i = 0; i < 4; ++i) {
            int row = w * 32 + i * 8 + lr;
            dma16(A + (size_t)(m0 + row) * 1024 + k0 + gch * 8,
                  As + (w * 32 + i * 8) * 64 + lane * 8);
            dma16(W + (size_t)(j0 + row) * 1024 + k0 + gch * 8,
                  Ws + (w * 32 + i * 8) * 64 + lane * 8);
        }
        __syncthreads();
#pragma unroll
        for (int ks = 0; ks < 2; ++ks) {
            int c = ks * 4 + quad;
            short8 af[4], bf[4];
#pragma unroll
            for (int i = 0; i < 4; ++i) {
                int ra = wm * 64 + i * 16 + fm;
                af[i] = *(const short8*)(As + ra * 64 + ((c ^ (ra & 7)) * 8));
                int rb = wn * 64 + i * 16 + fm;
                bf[i] = *(const short8*)(Ws + rb * 64 + ((c ^ (rb & 7)) * 8));
            }
#pragma unroll
            for (int i = 0; i < 4; ++i)
#pragma unroll
                for (int j = 0; j < 4; ++j)
                    acc[i][j] = __builtin_amdgcn_mfma_f32_16x16x32_bf16(af[i], bf[j], acc[i][j], 0, 0, 0);
        }
        __syncthreads();
    }

    if (z < 2) {
        u16* O = z ? Kb : Qb;
        const float* bias = z ? bk : bq;
#pragma unroll
        for (int j = 0; j < 4; ++j) {
            int jj = j0 + wn * 64 + j * 16 + fm;
            float bb = bias[jj];
#pragma unroll
            for (int i = 0; i < 4; ++i)
#pragma unroll
                for (int r = 0; r < 4; ++r) {
                    int m = m0 + wm * 64 + i * 16 + quad * 4 + r;
                    O[(size_t)m * 1024 + jj] = f2bf(acc[i][j][r] + bb);
                }
        }
    } else {
        // transpose through LDS, write PVt[j][p] coalesced
#pragma unroll
        for (int j = 0; j < 4; ++j) {
            int jl = wn * 64 + j * 16 + fm;
#pragma unroll
            for (int i = 0; i < 4; ++i) {
                int mlb = wm * 64 + i * 16 + quad * 4;
                ushort4 pk;
                pk.x = f2bf(acc[i][j][0]); pk.y = f2bf(acc[i][j][1]);
                pk.z = f2bf(acc[i][j][2]); pk.w = f2bf(acc[i][j][3]);
                *(ushort4*)(Tr + jl * 130 + mlb) = pk;
            }
        }
        __syncthreads();
#pragma unroll
        for (int i = 0; i < 8; ++i) {
            int f = i * 2048 + t * 8;
            int jl = f >> 7, ml = f & 127;
            short8 v = *(const short8*)(Tr + jl * 130 + ml);
            *(short8*)(PVt + (size_t)(j0 + jl) * PT + m0 + ml) = v;
        }
    }
}

// ---------------------------------------------------------------------------
// att: ATT[n][g][p] = (1/16) sum_d Qb[n,g*64+d]*Kb[p0+p,g*64+d], bf16 out.
// ---------------------------------------------------------------------------
__global__ __launch_bounds__(256)
void att_mfma(const u16* __restrict__ Qb, const u16* __restrict__ Kb,
              u16* __restrict__ ATT, const int* __restrict__ n1b_p,
              const int* __restrict__ n1p_p, int PT) {
    __shared__ __align__(16) u16 Qs[128 * 64];
    __shared__ __align__(16) u16 Ks[128 * 64];
    __shared__ __align__(16) u16 Tr[128 * 130];

    const int g = blockIdx.z;
    const int n0 = blockIdx.y * 128, pl0 = blockIdx.x * 128;
    const int n1b = *n1b_p, n1p = *n1p_p;
    const int hh = (n0 >= n1b) ? 1 : 0;
    const int p0 = hh ? n1p : 0;
    const int Ph = hh ? (PT - n1p) : n1p;
    if (pl0 >= Ph) return;
    const int t = threadIdx.x;
    const int w = t >> 6, lane = t & 63;
    const int wm = w >> 1, wn = w & 1;
    const int lr = lane >> 3, lc = lane & 7, gch = lc ^ lr;
    const int fm = lane & 15, quad = lane >> 4;

    float4v zero4 = {0.f, 0.f, 0.f, 0.f};
    float4v acc[4][4];
#pragma unroll
    for (int i = 0; i < 4; ++i)
#pragma unroll
        for (int j = 0; j < 4; ++j) acc[i][j] = zero4;

#pragma unroll
    for (int i = 0; i < 4; ++i) {
        int row = w * 32 + i * 8 + lr;
        dma16(Qb + (size_t)(n0 + row) * 1024 + g * 64 + gch * 8,
              Qs + (w * 32 + i * 8) * 64 + lane * 8);
        dma16(Kb + (size_t)(p0 + pl0 + row) * 1024 + g * 64 + gch * 8,
              Ks + (w * 32 + i * 8) * 64 + lane * 8);
    }
    __syncthreads();
#pragma unroll
    for (int ks = 0; ks < 2; ++ks) {
        int c = ks * 4 + quad;
        short8 af[4], bf[4];
#pragma unroll
        for (int i = 0; i < 4; ++i) {
            int ra = wm * 64 + i * 16 + fm;
            af[i] = *(const short8*)(Qs + ra * 64 + ((c ^ (ra & 7)) * 8));
            int rb = wn * 64 + i * 16 + fm;
            bf[i] = *(const short8*)(Ks + rb * 64 + ((c ^ (rb & 7)) * 8));
        }
#pragma unroll
        for (int i = 0; i < 4; ++i)
#pragma unroll
            for (int j = 0; j < 4; ++j)
                acc[i][j] = __builtin_amdgcn_mfma_f32_16x16x32_bf16(af[i], bf[j], acc[i][j], 0, 0, 0);
    }
    // stage result [n][p] into LDS, then coalesced global write
#pragma unroll
    for (int j = 0; j < 4; ++j) {
        int pl = wn * 64 + j * 16 + fm;
#pragma unroll
        for (int i = 0; i < 4; ++i)
#pragma unroll
            for (int r = 0; r < 4; ++r) {
                int nl = wm * 64 + i * 16 + quad * 4 + r;
                Tr[nl * 130 + pl] = f2bf(acc[i][j][r] * 0.0625f);
            }
    }
    __syncthreads();
#pragma unroll
    for (int i = 0; i < 8; ++i) {
        int f = i * 2048 + t * 8;
        int nl = f >> 7, pl = f & 127;
        short8 v = *(const short8*)(Tr + nl * 130 + pl);
        *(short8*)(ATT + ((size_t)(n0 + nl) * 16 + g) * 1024 + pl0 + pl) = v;
    }
}

// ---------------------------------------------------------------------------
// softmax: per-n block. pf via MFMA (E on the fly, Wg in regs),
// w = max(pf,1e-6)*exp(att), normalize, write sm (bf16, in-place in ATT).
// ---------------------------------------------------------------------------
__global__ __launch_bounds__(256)
void softmax_fused(const float* __restrict__ rois, const float* __restrict__ prois,
                   const float* __restrict__ Wg_w, const float* __restrict__ Wg_b,
                   u16* __restrict__ ATT, const int* __restrict__ n1b_p,
                   const int* __restrict__ n1p_p, int PT) {
    __shared__ __align__(16) u16 att_s[16 * 1032];
    __shared__ float redl[4][16];

    const int n = blockIdx.x, t = threadIdx.x;
    const int w = t >> 6, lane = t & 63;
    const int fm = lane & 15, quad = lane >> 4;
    const int n1b = *n1b_p, n1p = *n1p_p;
    const int hh = (n >= n1b) ? 1 : 0;
    const int p0 = hh ? n1p : 0;
    const int Ph = hh ? (PT - n1p) : n1p;   // 1024

    // stage att slice (coalesced)
#pragma unroll
    for (int i = 0; i < 8; ++i) {
        int e = i * 2048 + t * 8;
        int g = e >> 10, p = e & 1023;
        if (p < Ph) {
            short8 v = *(const short8*)(ATT + ((size_t)n * 16 + g) * 1024 + p);
            *(short8*)(att_s + g * 1032 + p) = v;
        }
    }

    // n-box
    float xmin = rois[n * 5 + 1], ymin = rois[n * 5 + 2];
    float xmax = rois[n * 5 + 3], ymax = rois[n * 5 + 4];
    float bw = xmax - xmin + 1.0f, bh = ymax - ymin + 1.0f;
    float cx = 0.5f * (xmin + xmax), cy = 0.5f * (ymin + ymax);

    // Wg b-fragments (held in registers; bias folded into acc init)
    const int g_ = fm;
    short8 b1, b2;
    {
        const float* w1 = Wg_w + g_ * 64 + quad * 8;
        const float* w2 = Wg_w + g_ * 64 + 32 + quad * 8;
#pragma unroll
        for (int jj = 0; jj < 8; ++jj) { b1[jj] = (short)f2bf(w1[jj]); b2[jj] = (short)f2bf(w2[jj]); }
    }
    float wgb = Wg_b[g_];
    __syncthreads();

    const float inv_em[8] = {1.0f, 0.4216965034f, 0.1778279410f, 0.0749894209f,
                             0.0316227766f, 0.0133352143f, 0.0056234133f, 0.0023713737f};
    const int jA = quad >> 1, trig = quad & 1;
    const int prange = Ph >> 2;              // p per wave (256)
    float Wreg[16][4];
    float ssum = 0.0f;

#pragma unroll
    for (int pt = 0; pt < 16; ++pt) {
        int pbase = w * prange + pt * 16;
        bool active = (pt * 16) < prange;
        float4v acc = {wgb, wgb, wgb, wgb};
        if (active) {
            int pi = pbase + fm;
            const float* pr = prois + (size_t)(p0 + pi) * 5;
            float pxmin = pr[1], pymin = pr[2], pxmax = pr[3], pymax = pr[4];
            float pw = pxmax - pxmin + 1.0f, ph2 = pymax - pymin + 1.0f;
            float pcx = 0.5f * (pxmin + pxmax), pcy = 0.5f * (pymin + pymax);
            float pos0 = __logf(fmaxf(fabsf((cx - pcx) / bw), 0.001f));
            float pos1 = __logf(fmaxf(fabsf((cy - pcy) / bh), 0.001f));
            float pos2 = __logf(pw / bw);
            float pos3 = __logf(ph2 / bh);
            float base1 = 100.0f * ((jA == 0) ? pos0 : pos1);
            float base2 = 100.0f * ((jA == 0) ? pos2 : pos3);
            short8 a1, a2;
#pragma unroll
            for (int k = 0; k < 8; ++k) {
                float ang1 = base1 * inv_em[k];
                float ang2 = base2 * inv_em[k];
                float v1 = trig ? __cosf(ang1) : __sinf(ang1);
                float v2 = trig ? __cosf(ang2) : __sinf(ang2);
                a1[k] = (short)f2bf(v1);
                a2[k] = (short)f2bf(v2);
            }
            acc = __builtin_amdgcn_mfma_f32_16x16x32_bf16(a1, b1, acc, 0, 0, 0);
            acc = __builtin_amdgcn_mfma_f32_16x16x32_bf16(a2, b2, acc, 0, 0, 0);
        }
#pragma unroll
        for (int r = 0; r < 4; ++r) {
            int p = pbase + quad * 4 + r;
            float wv = 0.0f;
            if (active) {
                float att = bf2f(att_s[g_ * 1032 + p]);
                wv = fmaxf(acc[r], 1e-6f) * __expf(att);
            }
            Wreg[pt][r] = wv;
            ssum += wv;
        }
    }

    ssum += __shfl_xor(ssum, 16, 64);
    ssum += __shfl_xor(ssum, 32, 64);
    if (lane < 16) redl[w][lane] = ssum;
    __syncthreads();
    float inv = 1.0f / (redl[0][g_] + redl[1][g_] + redl[2][g_] + redl[3][g_]);

#pragma unroll
    for (int pt = 0; pt < 16; ++pt) {
        if ((pt * 16) < prange) {
            int pb = w * prange + pt * 16 + quad * 4;
            ushort4 pk;
            pk.x = f2bf(Wreg[pt][0] * inv); pk.y = f2bf(Wreg[pt][1] * inv);
            pk.z = f2bf(Wreg[pt][2] * inv); pk.w = f2bf(Wreg[pt][3] * inv);
            *(ushort4*)(att_s + g_ * 1032 + pb) = pk;
        }
    }
    __syncthreads();
#pragma unroll
    for (int i = 0; i < 8; ++i) {
        int e = i * 2048 + t * 8;
        int g = e >> 10, p = e & 1023;
        if (p < Ph) {
            short8 v = *(const short8*)(att_s + g * 1032 + p);
            *(short8*)(ATT + ((size_t)n * 16 + g) * 1024 + p) = v;
        }
    }
}

// ---------------------------------------------------------------------------
// rel: OUT[n, g*64+o] = sum_p SM[n,g,p]*PVt[g*64+o, p0+p] + conv_b[g*64+o]
// tile 128n x 64o, BK=64, 4 waves (2x2), waves cover 64n x 32o each.
// ---------------------------------------------------------------------------
__global__ __launch_bounds__(256)
void rel_mfma(const u16* __restrict__ SM, const u16* __restrict__ PVt,
              const float* __restrict__ conv_b, float* __restrict__ OUT,
              const int* __restrict__ n1b_p, const int* __restrict__ n1p_p, int PT) {
    __shared__ __align__(16) u16 As[128 * 64];
    __shared__ __align__(16) u16 Bs[64 * 64];

    const int n0 = blockIdx.x * 128, g = blockIdx.y;
    const int n1b = *n1b_p, n1p = *n1p_p;
    const int hh = (n0 >= n1b) ? 1 : 0;
    const int p0 = hh ? n1p : 0;
    const int Ph = hh ? (PT - n1p) : n1p;
    const int t = threadIdx.x;
    const int w = t >> 6, lane = t & 63;
    const int wm = w >> 1, wn = w & 1;
    const int lr = lane >> 3, lc = lane & 7, gch = lc ^ lr;
    const int fm = lane & 15, quad = lane >> 4;

    float4v zero4 = {0.f, 0.f, 0.f, 0.f};
    float4v acc[4][2];
#pragma unroll
    for (int i = 0; i < 4; ++i) { acc[i][0] = zero4; acc[i][1] = zero4; }

    for (int k0 = 0; k0 < Ph; k0 += 64) {
#pragma unroll
        for (int i = 0; i < 4; ++i) {
            int row = w * 32 + i * 8 + lr;
            dma16(SM + ((size_t)(n0 + row) * 16 + g) * 1024 + k0 + gch * 8,
                  As + (w * 32 + i * 8) * 64 + lane * 8);
        }
#pragma unroll
        for (int i = 0; i < 2; ++i) {
            int row = w * 16 + i * 8 + lr;
            dma16(PVt + (size_t)(g * 64 + row) * PT + p0 + k0 + gch * 8,
                  Bs + (w * 16 + i * 8) * 64 + lane * 8);
        }
        __syncthreads();
#pragma unroll
        for (int ks = 0; ks < 2; ++ks) {
            int c = ks * 4 + quad;
            short8 af[4], bf[2];
#pragma unroll
            for (int i = 0; i < 4; ++i) {
                int ra = wm * 64 + i * 16 + fm;
                af[i] = *(const short8*)(As + ra * 64 + ((c ^ (ra & 7)) * 8));
            }
#pragma unroll
            for (int j = 0; j < 2; ++j) {
                int rb = wn * 32 + j * 16 + fm;
                bf[j] = *(const short8*)(Bs + rb * 64 + ((c ^ (rb & 7)) * 8));
            }
#pragma unroll
            for (int i = 0; i < 4; ++i)
#pragma unroll
                for (int j = 0; j < 2; ++j)
                    acc[i][j] = __builtin_amdgcn_mfma_f32_16x16x32_bf16(af[i], bf[j], acc[i][j], 0, 0, 0);
        }
        __syncthreads();
    }
#pragma unroll
    for (int j = 0; j < 2; ++j) {
        int o = wn * 32 + j * 16 + fm;
        float bb = conv_b[g * 64 + o];
#pragma unroll
        for (int i = 0; i < 4; ++i)
#pragma unroll
            for (int r = 0; r < 4; ++r) {
                int nn = n0 + wm * 64 + i * 16 + quad * 4 + r;
                OUT[(size_t)nn * 1024 + g * 64 + o] = acc[i][j][r] + bb;
            }
    }
}

extern "C" void kernel_launch(void* const* d_in, const int* in_sizes, int n_in,
                              void* d_out, int out_size, void* d_ws, size_t ws_size,
                              hipStream_t stream) {
    const float* rois   = (const float*)d_in[0];
    const float* prois  = (const float*)d_in[1];
    const float* bfeat  = (const float*)d_in[2];
    const float* pfeat  = (const float*)d_in[3];
    const float* Wg_w   = (const float*)d_in[4];
    const float* Wg_b   = (const float*)d_in[5];
    const float* Wq_w   = (const float*)d_in[6];
    const float* Wq_b   = (const float*)d_in[7];
    const float* Wk_w   = (const float*)d_in[8];
    const float* Wk_b   = (const float*)d_in[9];
    const float* conv_w = (const float*)d_in[10];
    const float* conv_b = (const float*)d_in[11];
    const int*   n1b    = (const int*)d_in[12];
    const int*   n1p    = (const int*)d_in[13];

    const int NT = in_sizes[2] / 1024;  // 2048
    const int PT = in_sizes[3] / 1024;  // 2048

    // ws layout (u16 elements). ATT (64 MB) is written AFTER proj consumes
    // the bf16 conversion buffers, so those alias ATT's storage.
    u16* ATT = (u16*)d_ws;                          // [NT][16][1024]
    u16* Qb  = ATT + (size_t)NT * 16 * 1024;        // [NT][1024]
    u16* Kb  = Qb + (size_t)NT * 1024;              // [PT][1024]
    u16* PVt = Kb + (size_t)PT * 1024;              // [1024][PT]
    u16* Ab  = ATT;                                 // aliases (consumed by proj)
    u16* Pb  = Ab + (size_t)NT * 1024;
    u16* Wqb = Pb + (size_t)PT * 1024;
    u16* Wkb = Wqb + 1024 * 1024;
    u16* Cwb = Wkb + 1024 * 1024;

    dim3 blk(256);
    int nf4 = NT * 1024 / 4, pf4 = PT * 1024 / 4, wf4 = 1024 * 1024 / 4;
    cvt_bf16<<<dim3((nf4 + 255) / 256), blk, 0, stream>>>(bfeat, Ab, nf4);
    cvt_bf16<<<dim3((pf4 + 255) / 256), blk, 0, stream>>>(pfeat, Pb, pf4);
    cvt_bf16<<<dim3((wf4 + 255) / 256), blk, 0, stream>>>(Wq_w, Wqb, wf4);
    cvt_bf16<<<dim3((wf4 + 255) / 256), blk, 0, stream>>>(Wk_w, Wkb, wf4);
    cvt_bf16<<<dim3((wf4 + 255) / 256), blk, 0, stream>>>(conv_w, Cwb, wf4);

    proj_mfma<<<dim3(8, NT / 128, 3), blk, 0, stream>>>(Ab, Pb, Wqb, Wkb, Cwb,
                                                        Wq_b, Wk_b, Qb, Kb, PVt, PT);
    att_mfma<<<dim3(PT / 128, NT / 128, 16), blk, 0, stream>>>(Qb, Kb, ATT, n1b, n1p, PT);
    softmax_fused<<<dim3(NT), blk, 0, stream>>>(rois, prois, Wg_w, Wg_b, ATT, n1b, n1p, PT);
    rel_mfma<<<dim3(NT / 128, 16), blk, 0, stream>>>(ATT, PVt, conv_b, (float*)d_out, n1b, n1p, PT);
}

// Round 4
// 250.659 us; speedup vs baseline: 2.3841x; 1.0295x over previous
//
#include <hip/hip_runtime.h>

typedef unsigned short u16;
using short8  = __attribute__((ext_vector_type(8))) short;
using float4v = __attribute__((ext_vector_type(4))) float;

__device__ __forceinline__ u16 f2bf(float f) {
    union { float f; unsigned u; } v; v.f = f;
    unsigned r = (v.u + 0x7fff + ((v.u >> 16) & 1)) >> 16;
    return (u16)r;
}
__device__ __forceinline__ float bf2f(u16 h) {
    union { unsigned u; float f; } v; v.u = ((unsigned)h) << 16; return v.f;
}
__device__ __forceinline__ void dma16(const void* g, void* l) {
    __builtin_amdgcn_global_load_lds((const __attribute__((address_space(1))) void*)g,
                                     (__attribute__((address_space(3))) void*)l, 16, 0, 0);
}

// ---------------------------------------------------------------------------
// merged f32 -> bf16 bulk convert for all five tensors (one launch)
// ---------------------------------------------------------------------------
__global__ __launch_bounds__(256)
void cvt_all(const float* __restrict__ s0, const float* __restrict__ s1,
             const float* __restrict__ s2, const float* __restrict__ s3,
             const float* __restrict__ s4,
             u16* __restrict__ o0, u16* __restrict__ o1, u16* __restrict__ o2,
             u16* __restrict__ o3, u16* __restrict__ o4,
             int na4, int nb4, int nw4) {
    int i = blockIdx.x * 256 + threadIdx.x;
    const float* s; u16* o;
    if (i < na4) { s = s0; o = o0; }
    else {
        i -= na4;
        if (i < nb4) { s = s1; o = o1; }
        else {
            i -= nb4;
            if (i < nw4) { s = s2; o = o2; }
            else {
                i -= nw4;
                if (i < nw4) { s = s3; o = o3; }
                else {
                    i -= nw4;
                    if (i >= nw4) return;
                    s = s4; o = o4;
                }
            }
        }
    }
    float4 v = ((const float4*)s)[i];
    ushort4 t;
    t.x = f2bf(v.x); t.y = f2bf(v.y); t.z = f2bf(v.z); t.w = f2bf(v.w);
    ((ushort4*)o)[i] = t;
}

// ---------------------------------------------------------------------------
// proj: C[m,j] = sum_k A[m,k]*W[j,k] (+bias). z=0: Q, z=1: K, z=2: PV->PVt.
// 128x128 tile, BK=64, 4 waves (2x2), 4x4 subtiles of 16x16x32 MFMA.
// ---------------------------------------------------------------------------
__global__ __launch_bounds__(256)
void proj_mfma(const u16* __restrict__ Ab, const u16* __restrict__ Pb,
               const u16* __restrict__ Wqb, const u16* __restrict__ Wkb,
               const u16* __restrict__ Cwb, const float* __restrict__ bq,
               const float* __restrict__ bk, u16* __restrict__ Qb,
               u16* __restrict__ Kb, u16* __restrict__ PVt, int PT) {
    __shared__ __align__(16) u16 As[128 * 64];
    __shared__ __align__(16) u16 Ws[128 * 64];
    __shared__ __align__(16) u16 Tr[128 * 130];

    const int z = blockIdx.z;
    const int m0 = blockIdx.y * 128, j0 = blockIdx.x * 128;
    const u16* A = (z == 0) ? Ab : Pb;
    const u16* W = (z == 0) ? Wqb : (z == 1 ? Wkb : Cwb);
    const int t = threadIdx.x;
    const int w = t >> 6, lane = t & 63;
    const int wm = w >> 1, wn = w & 1;
    const int lr = lane >> 3, lc = lane & 7, gch = lc ^ lr;
    const int fm = lane & 15, quad = lane >> 4;

    float4v zero4 = {0.f, 0.f, 0.f, 0.f};
    float4v acc[4][4];
#pragma unroll
    for (int i = 0; i < 4; ++i)
#pragma unroll
        for (int j = 0; j < 4; ++j) acc[i][j] = zero4;

    for (int k0 = 0; k0 < 1024; k0 += 64) {
#pragma unroll
        for (int i = 0; i < 4; ++i) {
            int row = w * 32 + i * 8 + lr;
            dma16(A + (size_t)(m0 + row) * 1024 + k0 + gch * 8,
                  As + (w * 32 + i * 8) * 64 + lane * 8);
            dma16(W + (size_t)(j0 + row) * 1024 + k0 + gch * 8,
                  Ws + (w * 32 + i * 8) * 64 + lane * 8);
        }
        __syncthreads();
#pragma unroll
        for (int ks = 0; ks < 2; ++ks) {
            int c = ks * 4 + quad;
            short8 af[4], bf[4];
#pragma unroll
            for (int i = 0; i < 4; ++i) {
                int ra = wm * 64 + i * 16 + fm;
                af[i] = *(const short8*)(As + ra * 64 + ((c ^ (ra & 7)) * 8));
                int rb = wn * 64 + i * 16 + fm;
                bf[i] = *(const short8*)(Ws + rb * 64 + ((c ^ (rb & 7)) * 8));
            }
#pragma unroll
            for (int i = 0; i < 4; ++i)
#pragma unroll
                for (int j = 0; j < 4; ++j)
                    acc[i][j] = __builtin_amdgcn_mfma_f32_16x16x32_bf16(af[i], bf[j], acc[i][j], 0, 0, 0);
        }
        __syncthreads();
    }

    if (z < 2) {
        u16* O = z ? Kb : Qb;
        const float* bias = z ? bk : bq;
#pragma unroll
        for (int j = 0; j < 4; ++j) {
            int jj = j0 + wn * 64 + j * 16 + fm;
            float bb = bias[jj];
#pragma unroll
            for (int i = 0; i < 4; ++i)
#pragma unroll
                for (int r = 0; r < 4; ++r) {
                    int m = m0 + wm * 64 + i * 16 + quad * 4 + r;
                    O[(size_t)m * 1024 + jj] = f2bf(acc[i][j][r] + bb);
                }
        }
    } else {
        // transpose through LDS, write PVt[j][p] coalesced
#pragma unroll
        for (int j = 0; j < 4; ++j) {
            int jl = wn * 64 + j * 16 + fm;
#pragma unroll
            for (int i = 0; i < 4; ++i) {
                int mlb = wm * 64 + i * 16 + quad * 4;
                ushort4 pk;
                pk.x = f2bf(acc[i][j][0]); pk.y = f2bf(acc[i][j][1]);
                pk.z = f2bf(acc[i][j][2]); pk.w = f2bf(acc[i][j][3]);
                *(ushort4*)(Tr + jl * 130 + mlb) = pk;
            }
        }
        __syncthreads();
#pragma unroll
        for (int i = 0; i < 8; ++i) {
            int f = i * 2048 + t * 8;
            int jl = f >> 7, ml = f & 127;
            short8 v = *(const short8*)(Tr + jl * 130 + ml);
            *(short8*)(PVt + (size_t)(j0 + jl) * PT + m0 + ml) = v;
        }
    }
}

// ---------------------------------------------------------------------------
// att: ATT[n][g][p] = (1/16) sum_d Qb[n,g*64+d]*Kb[p0+p,g*64+d], bf16 out.
// ---------------------------------------------------------------------------
__global__ __launch_bounds__(256)
void att_mfma(const u16* __restrict__ Qb, const u16* __restrict__ Kb,
              u16* __restrict__ ATT, const int* __restrict__ n1b_p,
              const int* __restrict__ n1p_p, int PT) {
    __shared__ __align__(16) u16 Qs[128 * 64];
    __shared__ __align__(16) u16 Ks[128 * 64];
    __shared__ __align__(16) u16 Tr[128 * 130];

    const int g = blockIdx.z;
    const int n0 = blockIdx.y * 128, pl0 = blockIdx.x * 128;
    const int n1b = *n1b_p, n1p = *n1p_p;
    const int hh = (n0 >= n1b) ? 1 : 0;
    const int p0 = hh ? n1p : 0;
    const int Ph = hh ? (PT - n1p) : n1p;
    if (pl0 >= Ph) return;
    const int t = threadIdx.x;
    const int w = t >> 6, lane = t & 63;
    const int wm = w >> 1, wn = w & 1;
    const int lr = lane >> 3, lc = lane & 7, gch = lc ^ lr;
    const int fm = lane & 15, quad = lane >> 4;

    float4v zero4 = {0.f, 0.f, 0.f, 0.f};
    float4v acc[4][4];
#pragma unroll
    for (int i = 0; i < 4; ++i)
#pragma unroll
        for (int j = 0; j < 4; ++j) acc[i][j] = zero4;

#pragma unroll
    for (int i = 0; i < 4; ++i) {
        int row = w * 32 + i * 8 + lr;
        dma16(Qb + (size_t)(n0 + row) * 1024 + g * 64 + gch * 8,
              Qs + (w * 32 + i * 8) * 64 + lane * 8);
        dma16(Kb + (size_t)(p0 + pl0 + row) * 1024 + g * 64 + gch * 8,
              Ks + (w * 32 + i * 8) * 64 + lane * 8);
    }
    __syncthreads();
#pragma unroll
    for (int ks = 0; ks < 2; ++ks) {
        int c = ks * 4 + quad;
        short8 af[4], bf[4];
#pragma unroll
        for (int i = 0; i < 4; ++i) {
            int ra = wm * 64 + i * 16 + fm;
            af[i] = *(const short8*)(Qs + ra * 64 + ((c ^ (ra & 7)) * 8));
            int rb = wn * 64 + i * 16 + fm;
            bf[i] = *(const short8*)(Ks + rb * 64 + ((c ^ (rb & 7)) * 8));
        }
#pragma unroll
        for (int i = 0; i < 4; ++i)
#pragma unroll
            for (int j = 0; j < 4; ++j)
                acc[i][j] = __builtin_amdgcn_mfma_f32_16x16x32_bf16(af[i], bf[j], acc[i][j], 0, 0, 0);
    }
    // stage result [n][p] into LDS, then coalesced global write
#pragma unroll
    for (int j = 0; j < 4; ++j) {
        int pl = wn * 64 + j * 16 + fm;
#pragma unroll
        for (int i = 0; i < 4; ++i)
#pragma unroll
            for (int r = 0; r < 4; ++r) {
                int nl = wm * 64 + i * 16 + quad * 4 + r;
                Tr[nl * 130 + pl] = f2bf(acc[i][j][r] * 0.0625f);
            }
    }
    __syncthreads();
#pragma unroll
    for (int i = 0; i < 8; ++i) {
        int f = i * 2048 + t * 8;
        int nl = f >> 7, pl = f & 127;
        short8 v = *(const short8*)(Tr + nl * 130 + pl);
        *(short8*)(ATT + ((size_t)(n0 + nl) * 16 + g) * 1024 + pl0 + pl) = v;
    }
}

// ---------------------------------------------------------------------------
// softmax: per-n block. pf via MFMA (E on the fly, Wg in regs).
// Pass 1: w = max(pf,1e-6)*exp(att) written in place (bf16, LDS) + ssum.
// Pass 2: normalize from LDS, coalesced write to ATT. No per-thread arrays.
// ---------------------------------------------------------------------------
__global__ __launch_bounds__(256)
void softmax_fused(const float* __restrict__ rois, const float* __restrict__ prois,
                   const float* __restrict__ Wg_w, const float* __restrict__ Wg_b,
                   u16* __restrict__ ATT, const int* __restrict__ n1b_p,
                   const int* __restrict__ n1p_p, int PT) {
    __shared__ __align__(16) u16 att_s[16 * 1032];
    __shared__ float redl[4][16];
    __shared__ float redt[16];

    const int n = blockIdx.x, t = threadIdx.x;
    const int w = t >> 6, lane = t & 63;
    const int fm = lane & 15, quad = lane >> 4;
    const int n1b = *n1b_p, n1p = *n1p_p;
    const int hh = (n >= n1b) ? 1 : 0;
    const int p0 = hh ? n1p : 0;
    const int Ph = hh ? (PT - n1p) : n1p;   // 1024

    // stage att slice (coalesced)
#pragma unroll
    for (int i = 0; i < 8; ++i) {
        int e = i * 2048 + t * 8;
        int g = e >> 10, p = e & 1023;
        if (p < Ph) {
            short8 v = *(const short8*)(ATT + ((size_t)n * 16 + g) * 1024 + p);
            *(short8*)(att_s + g * 1032 + p) = v;
        }
    }

    // n-box
    float xmin = rois[n * 5 + 1], ymin = rois[n * 5 + 2];
    float xmax = rois[n * 5 + 3], ymax = rois[n * 5 + 4];
    float bw = xmax - xmin + 1.0f, bh = ymax - ymin + 1.0f;
    float cx = 0.5f * (xmin + xmax), cy = 0.5f * (ymin + ymax);

    // Wg b-fragments (held in registers; bias folded into acc init)
    const int g_ = fm;
    short8 b1, b2;
    {
        const float* w1 = Wg_w + g_ * 64 + quad * 8;
        const float* w2 = Wg_w + g_ * 64 + 32 + quad * 8;
#pragma unroll
        for (int jj = 0; jj < 8; ++jj) { b1[jj] = (short)f2bf(w1[jj]); b2[jj] = (short)f2bf(w2[jj]); }
    }
    float wgb = Wg_b[g_];
    __syncthreads();

    const float inv_em[8] = {1.0f, 0.4216965034f, 0.1778279410f, 0.0749894209f,
                             0.0316227766f, 0.0133352143f, 0.0056234133f, 0.0023713737f};
    const int jA = quad >> 1, trig = quad & 1;
    const int prange = Ph >> 2;              // p per wave (256)
    float ssum = 0.0f;

#pragma unroll 2
    for (int pt = 0; pt < 16; ++pt) {
        int pbase = w * prange + pt * 16;
        bool active = (pt * 16) < prange;
        float4v acc = {wgb, wgb, wgb, wgb};
        if (active) {
            int pi = pbase + fm;
            const float* pr = prois + (size_t)(p0 + pi) * 5;
            float pxmin = pr[1], pymin = pr[2], pxmax = pr[3], pymax = pr[4];
            float pw = pxmax - pxmin + 1.0f, ph2 = pymax - pymin + 1.0f;
            float pcx = 0.5f * (pxmin + pxmax), pcy = 0.5f * (pymin + pymax);
            float pos0 = __logf(fmaxf(fabsf((cx - pcx) / bw), 0.001f));
            float pos1 = __logf(fmaxf(fabsf((cy - pcy) / bh), 0.001f));
            float pos2 = __logf(pw / bw);
            float pos3 = __logf(ph2 / bh);
            float base1 = 100.0f * ((jA == 0) ? pos0 : pos1);
            float base2 = 100.0f * ((jA == 0) ? pos2 : pos3);
            short8 a1, a2;
#pragma unroll
            for (int k = 0; k < 8; ++k) {
                float ang1 = base1 * inv_em[k];
                float ang2 = base2 * inv_em[k];
                float v1 = trig ? __cosf(ang1) : __sinf(ang1);
                float v2 = trig ? __cosf(ang2) : __sinf(ang2);
                a1[k] = (short)f2bf(v1);
                a2[k] = (short)f2bf(v2);
            }
            acc = __builtin_amdgcn_mfma_f32_16x16x32_bf16(a1, b1, acc, 0, 0, 0);
            acc = __builtin_amdgcn_mfma_f32_16x16x32_bf16(a2, b2, acc, 0, 0, 0);
#pragma unroll
            for (int r = 0; r < 4; ++r) {
                int p = pbase + quad * 4 + r;
                float att = bf2f(att_s[g_ * 1032 + p]);
                float wv = fmaxf(acc[r], 1e-6f) * __expf(att);
                att_s[g_ * 1032 + p] = f2bf(wv);
                ssum += wv;
            }
        }
    }

    ssum += __shfl_xor(ssum, 16, 64);
    ssum += __shfl_xor(ssum, 32, 64);
    if (lane < 16) redl[w][lane] = ssum;
    __syncthreads();
    if (t < 16) redt[t] = 1.0f / (redl[0][t] + redl[1][t] + redl[2][t] + redl[3][t]);
    __syncthreads();

#pragma unroll
    for (int i = 0; i < 8; ++i) {
        int e = i * 2048 + t * 8;
        int g = e >> 10, p = e & 1023;
        if (p < Ph) {
            float inv = redt[g];
            short8 v = *(const short8*)(att_s + g * 1032 + p);
            ushort4 oa, ob;
            oa.x = f2bf(bf2f((u16)v[0]) * inv); oa.y = f2bf(bf2f((u16)v[1]) * inv);
            oa.z = f2bf(bf2f((u16)v[2]) * inv); oa.w = f2bf(bf2f((u16)v[3]) * inv);
            ob.x = f2bf(bf2f((u16)v[4]) * inv); ob.y = f2bf(bf2f((u16)v[5]) * inv);
            ob.z = f2bf(bf2f((u16)v[6]) * inv); ob.w = f2bf(bf2f((u16)v[7]) * inv);
            u16* dst = ATT + ((size_t)n * 16 + g) * 1024 + p;
            *(ushort4*)dst = oa;
            *(ushort4*)(dst + 4) = ob;
        }
    }
}

// ---------------------------------------------------------------------------
// rel: OUT[n, g*64+o] = sum_p SM[n,g,p]*PVt[g*64+o, p0+p] + conv_b[g*64+o]
// tile 128n x 64o, BK=64, 4 waves (2x2), waves cover 64n x 32o each.
// ---------------------------------------------------------------------------
__global__ __launch_bounds__(256)
void rel_mfma(const u16* __restrict__ SM, const u16* __restrict__ PVt,
              const float* __restrict__ conv_b, float* __restrict__ OUT,
              const int* __restrict__ n1b_p, const int* __restrict__ n1p_p, int PT) {
    __shared__ __align__(16) u16 As[128 * 64];
    __shared__ __align__(16) u16 Bs[64 * 64];

    const int n0 = blockIdx.x * 128, g = blockIdx.y;
    const int n1b = *n1b_p, n1p = *n1p_p;
    const int hh = (n0 >= n1b) ? 1 : 0;
    const int p0 = hh ? n1p : 0;
    const int Ph = hh ? (PT - n1p) : n1p;
    const int t = threadIdx.x;
    const int w = t >> 6, lane = t & 63;
    const int wm = w >> 1, wn = w & 1;
    const int lr = lane >> 3, lc = lane & 7, gch = lc ^ lr;
    const int fm = lane & 15, quad = lane >> 4;

    float4v zero4 = {0.f, 0.f, 0.f, 0.f};
    float4v acc[4][2];
#pragma unroll
    for (int i = 0; i < 4; ++i) { acc[i][0] = zero4; acc[i][1] = zero4; }

    for (int k0 = 0; k0 < Ph; k0 += 64) {
#pragma unroll
        for (int i = 0; i < 4; ++i) {
            int row = w * 32 + i * 8 + lr;
            dma16(SM + ((size_t)(n0 + row) * 16 + g) * 1024 + k0 + gch * 8,
                  As + (w * 32 + i * 8) * 64 + lane * 8);
        }
#pragma unroll
        for (int i = 0; i < 2; ++i) {
            int row = w * 16 + i * 8 + lr;
            dma16(PVt + (size_t)(g * 64 + row) * PT + p0 + k0 + gch * 8,
                  Bs + (w * 16 + i * 8) * 64 + lane * 8);
        }
        __syncthreads();
#pragma unroll
        for (int ks = 0; ks < 2; ++ks) {
            int c = ks * 4 + quad;
            short8 af[4], bf[2];
#pragma unroll
            for (int i = 0; i < 4; ++i) {
                int ra = wm * 64 + i * 16 + fm;
                af[i] = *(const short8*)(As + ra * 64 + ((c ^ (ra & 7)) * 8));
            }
#pragma unroll
            for (int j = 0; j < 2; ++j) {
                int rb = wn * 32 + j * 16 + fm;
                bf[j] = *(const short8*)(Bs + rb * 64 + ((c ^ (rb & 7)) * 8));
            }
#pragma unroll
            for (int i = 0; i < 4; ++i)
#pragma unroll
                for (int j = 0; j < 2; ++j)
                    acc[i][j] = __builtin_amdgcn_mfma_f32_16x16x32_bf16(af[i], bf[j], acc[i][j], 0, 0, 0);
        }
        __syncthreads();
    }
#pragma unroll
    for (int j = 0; j < 2; ++j) {
        int o = wn * 32 + j * 16 + fm;
        float bb = conv_b[g * 64 + o];
#pragma unroll
        for (int i = 0; i < 4; ++i)
#pragma unroll
            for (int r = 0; r < 4; ++r) {
                int nn = n0 + wm * 64 + i * 16 + quad * 4 + r;
                OUT[(size_t)nn * 1024 + g * 64 + o] = acc[i][j][r] + bb;
            }
    }
}

extern "C" void kernel_launch(void* const* d_in, const int* in_sizes, int n_in,
                              void* d_out, int out_size, void* d_ws, size_t ws_size,
                              hipStream_t stream) {
    const float* rois   = (const float*)d_in[0];
    const float* prois  = (const float*)d_in[1];
    const float* bfeat  = (const float*)d_in[2];
    const float* pfeat  = (const float*)d_in[3];
    const float* Wg_w   = (const float*)d_in[4];
    const float* Wg_b   = (const float*)d_in[5];
    const float* Wq_w   = (const float*)d_in[6];
    const float* Wq_b   = (const float*)d_in[7];
    const float* Wk_w   = (const float*)d_in[8];
    const float* Wk_b   = (const float*)d_in[9];
    const float* conv_w = (const float*)d_in[10];
    const float* conv_b = (const float*)d_in[11];
    const int*   n1b    = (const int*)d_in[12];
    const int*   n1p    = (const int*)d_in[13];

    const int NT = in_sizes[2] / 1024;  // 2048
    const int PT = in_sizes[3] / 1024;  // 2048

    // ws layout (u16 elements). ATT (64 MB) is written AFTER proj consumes
    // the bf16 conversion buffers, so those alias ATT's storage.
    u16* ATT = (u16*)d_ws;                          // [NT][16][1024]
    u16* Qb  = ATT + (size_t)NT * 16 * 1024;        // [NT][1024]
    u16* Kb  = Qb + (size_t)NT * 1024;              // [PT][1024]
    u16* PVt = Kb + (size_t)PT * 1024;              // [1024][PT]
    u16* Ab  = ATT;                                 // aliases (consumed by proj)
    u16* Pb  = Ab + (size_t)NT * 1024;
    u16* Wqb = Pb + (size_t)PT * 1024;
    u16* Wkb = Wqb + 1024 * 1024;
    u16* Cwb = Wkb + 1024 * 1024;

    dim3 blk(256);
    int nf4 = NT * 1024 / 4, pf4 = PT * 1024 / 4, wf4 = 1024 * 1024 / 4;
    int tot4 = nf4 + pf4 + 3 * wf4;
    cvt_all<<<dim3((tot4 + 255) / 256), blk, 0, stream>>>(
        bfeat, pfeat, Wq_w, Wk_w, conv_w, Ab, Pb, Wqb, Wkb, Cwb, nf4, pf4, wf4);

    proj_mfma<<<dim3(8, NT / 128, 3), blk, 0, stream>>>(Ab, Pb, Wqb, Wkb, Cwb,
                                                        Wq_b, Wk_b, Qb, Kb, PVt, PT);
    att_mfma<<<dim3(PT / 128, NT / 128, 16), blk, 0, stream>>>(Qb, Kb, ATT, n1b, n1p, PT);
    softmax_fused<<<dim3(NT), blk, 0, stream>>>(rois, prois, Wg_w, Wg_b, ATT, n1b, n1p, PT);
    rel_mfma<<<dim3(NT / 128, 16), blk, 0, stream>>>(ATT, PVt, conv_b, (float*)d_out, n1b, n1p, PT);
}

// Round 5
// 225.287 us; speedup vs baseline: 2.6526x; 1.1126x over previous
//
#include <hip/hip_runtime.h>

typedef unsigned short u16;
using short8  = __attribute__((ext_vector_type(8))) short;
using float4v = __attribute__((ext_vector_type(4))) float;

__device__ __forceinline__ u16 f2bf(float f) {
    union { float f; unsigned u; } v; v.f = f;
    unsigned r = (v.u + 0x7fff + ((v.u >> 16) & 1)) >> 16;
    return (u16)r;
}
__device__ __forceinline__ float bf2f(u16 h) {
    union { unsigned u; float f; } v; v.u = ((unsigned)h) << 16; return v.f;
}
// HW packed f32x2 -> bf16x2 (lo in low 16 bits). CDNA3+/gfx950.
__device__ __forceinline__ unsigned pkbf(float lo, float hi) {
    unsigned d;
    asm("v_cvt_pk_bf16_f32 %0, %1, %2" : "=v"(d) : "v"(lo), "v"(hi));
    return d;
}
__device__ __forceinline__ void dma16(const void* g, void* l) {
    __builtin_amdgcn_global_load_lds((const __attribute__((address_space(1))) void*)g,
                                     (__attribute__((address_space(3))) void*)l, 16, 0, 0);
}

// ---------------------------------------------------------------------------
// merged f32 -> bf16 bulk convert for five tensors + PD precompute
// PD[p] = (pcx, pcy, log(pw), log(ph))
// ---------------------------------------------------------------------------
__device__ __forceinline__ void cvt4(const float* __restrict__ s, u16* __restrict__ o, int i) {
    float4 v = ((const float4*)s)[i];
    uint2 r; r.x = pkbf(v.x, v.y); r.y = pkbf(v.z, v.w);
    ((uint2*)o)[i] = r;
}

__global__ __launch_bounds__(256)
void cvt_all(const float* __restrict__ s0, const float* __restrict__ s1,
             const float* __restrict__ s2, const float* __restrict__ s3,
             const float* __restrict__ s4, const float* __restrict__ prois,
             u16* __restrict__ o0, u16* __restrict__ o1, u16* __restrict__ o2,
             u16* __restrict__ o3, u16* __restrict__ o4, float4* __restrict__ PD,
             int na4, int nb4, int nw4, int PT) {
    int i = blockIdx.x * 256 + threadIdx.x;
    if (i < na4) { cvt4(s0, o0, i); return; }
    i -= na4;
    if (i < nb4) { cvt4(s1, o1, i); return; }
    i -= nb4;
    if (i < nw4) { cvt4(s2, o2, i); return; }
    i -= nw4;
    if (i < nw4) { cvt4(s3, o3, i); return; }
    i -= nw4;
    if (i < nw4) { cvt4(s4, o4, i); return; }
    i -= nw4;
    if (i < PT) {
        const float* pr = prois + (size_t)i * 5;
        float pxmin = pr[1], pymin = pr[2], pxmax = pr[3], pymax = pr[4];
        PD[i] = make_float4(0.5f * (pxmin + pxmax), 0.5f * (pymin + pymax),
                            __logf(pxmax - pxmin + 1.0f), __logf(pymax - pymin + 1.0f));
    }
}

// ---------------------------------------------------------------------------
// proj: C[m,j] = sum_k A[m,k]*W[j,k] (+bias). z=0: Q, z=1: K, z=2: PV->PVt.
// ---------------------------------------------------------------------------
__global__ __launch_bounds__(256)
void proj_mfma(const u16* __restrict__ Ab, const u16* __restrict__ Pb,
               const u16* __restrict__ Wqb, const u16* __restrict__ Wkb,
               const u16* __restrict__ Cwb, const float* __restrict__ bq,
               const float* __restrict__ bk, u16* __restrict__ Qb,
               u16* __restrict__ Kb, u16* __restrict__ PVt, int PT) {
    __shared__ __align__(16) u16 As[128 * 64];
    __shared__ __align__(16) u16 Ws[128 * 64];
    __shared__ __align__(16) u16 Tr[128 * 130];

    const int z = blockIdx.z;
    const int m0 = blockIdx.y * 128, j0 = blockIdx.x * 128;
    const u16* A = (z == 0) ? Ab : Pb;
    const u16* W = (z == 0) ? Wqb : (z == 1 ? Wkb : Cwb);
    const int t = threadIdx.x;
    const int w = t >> 6, lane = t & 63;
    const int wm = w >> 1, wn = w & 1;
    const int lr = lane >> 3, lc = lane & 7, gch = lc ^ lr;
    const int fm = lane & 15, quad = lane >> 4;

    float4v zero4 = {0.f, 0.f, 0.f, 0.f};
    float4v acc[4][4];
#pragma unroll
    for (int i = 0; i < 4; ++i)
#pragma unroll
        for (int j = 0; j < 4; ++j) acc[i][j] = zero4;

    for (int k0 = 0; k0 < 1024; k0 += 64) {
#pragma unroll
        for (int i = 0; i < 4; ++i) {
            int row = w * 32 + i * 8 + lr;
            dma16(A + (size_t)(m0 + row) * 1024 + k0 + gch * 8,
                  As + (w * 32 + i * 8) * 64 + lane * 8);
            dma16(W + (size_t)(j0 + row) * 1024 + k0 + gch * 8,
                  Ws + (w * 32 + i * 8) * 64 + lane * 8);
        }
        __syncthreads();
#pragma unroll
        for (int ks = 0; ks < 2; ++ks) {
            int c = ks * 4 + quad;
            short8 af[4], bf[4];
#pragma unroll
            for (int i = 0; i < 4; ++i) {
                int ra = wm * 64 + i * 16 + fm;
                af[i] = *(const short8*)(As + ra * 64 + ((c ^ (ra & 7)) * 8));
                int rb = wn * 64 + i * 16 + fm;
                bf[i] = *(const short8*)(Ws + rb * 64 + ((c ^ (rb & 7)) * 8));
            }
#pragma unroll
            for (int i = 0; i < 4; ++i)
#pragma unroll
                for (int j = 0; j < 4; ++j)
                    acc[i][j] = __builtin_amdgcn_mfma_f32_16x16x32_bf16(af[i], bf[j], acc[i][j], 0, 0, 0);
        }
        __syncthreads();
    }

    if (z < 2) {
        u16* O = z ? Kb : Qb;
        const float* bias = z ? bk : bq;
#pragma unroll
        for (int j = 0; j < 4; ++j) {
            int jj = j0 + wn * 64 + j * 16 + fm;
            float bb = bias[jj];
#pragma unroll
            for (int i = 0; i < 4; ++i)
#pragma unroll
                for (int r = 0; r < 4; ++r) {
                    int m = m0 + wm * 64 + i * 16 + quad * 4 + r;
                    O[(size_t)m * 1024 + jj] = f2bf(acc[i][j][r] + bb);
                }
        }
    } else {
#pragma unroll
        for (int j = 0; j < 4; ++j) {
            int jl = wn * 64 + j * 16 + fm;
#pragma unroll
            for (int i = 0; i < 4; ++i) {
                int mlb = wm * 64 + i * 16 + quad * 4;
                uint2 pk;
                pk.x = pkbf(acc[i][j][0], acc[i][j][1]);
                pk.y = pkbf(acc[i][j][2], acc[i][j][3]);
                *(uint2*)(Tr + jl * 130 + mlb) = pk;
            }
        }
        __syncthreads();
#pragma unroll
        for (int i = 0; i < 8; ++i) {
            int f = i * 2048 + t * 8;
            int jl = f >> 7, ml = f & 127;
            short8 v = *(const short8*)(Tr + jl * 130 + ml);
            *(short8*)(PVt + (size_t)(j0 + jl) * PT + m0 + ml) = v;
        }
    }
}

// ---------------------------------------------------------------------------
// att: ATT[n][g][p] = exp((1/16) sum_d Q*K)  -- exp folded in, bf16 out.
// ---------------------------------------------------------------------------
__global__ __launch_bounds__(256)
void att_mfma(const u16* __restrict__ Qb, const u16* __restrict__ Kb,
              u16* __restrict__ ATT, const int* __restrict__ n1b_p,
              const int* __restrict__ n1p_p, int PT) {
    __shared__ __align__(16) u16 Qs[128 * 64];
    __shared__ __align__(16) u16 Ks[128 * 64];
    __shared__ __align__(16) u16 Tr[128 * 130];

    const int g = blockIdx.z;
    const int n0 = blockIdx.y * 128, pl0 = blockIdx.x * 128;
    const int n1b = *n1b_p, n1p = *n1p_p;
    const int hh = (n0 >= n1b) ? 1 : 0;
    const int p0 = hh ? n1p : 0;
    const int Ph = hh ? (PT - n1p) : n1p;
    if (pl0 >= Ph) return;
    const int t = threadIdx.x;
    const int w = t >> 6, lane = t & 63;
    const int wm = w >> 1, wn = w & 1;
    const int lr = lane >> 3, lc = lane & 7, gch = lc ^ lr;
    const int fm = lane & 15, quad = lane >> 4;

    float4v zero4 = {0.f, 0.f, 0.f, 0.f};
    float4v acc[4][4];
#pragma unroll
    for (int i = 0; i < 4; ++i)
#pragma unroll
        for (int j = 0; j < 4; ++j) acc[i][j] = zero4;

#pragma unroll
    for (int i = 0; i < 4; ++i) {
        int row = w * 32 + i * 8 + lr;
        dma16(Qb + (size_t)(n0 + row) * 1024 + g * 64 + gch * 8,
              Qs + (w * 32 + i * 8) * 64 + lane * 8);
        dma16(Kb + (size_t)(p0 + pl0 + row) * 1024 + g * 64 + gch * 8,
              Ks + (w * 32 + i * 8) * 64 + lane * 8);
    }
    __syncthreads();
#pragma unroll
    for (int ks = 0; ks < 2; ++ks) {
        int c = ks * 4 + quad;
        short8 af[4], bf[4];
#pragma unroll
        for (int i = 0; i < 4; ++i) {
            int ra = wm * 64 + i * 16 + fm;
            af[i] = *(const short8*)(Qs + ra * 64 + ((c ^ (ra & 7)) * 8));
            int rb = wn * 64 + i * 16 + fm;
            bf[i] = *(const short8*)(Ks + rb * 64 + ((c ^ (rb & 7)) * 8));
        }
#pragma unroll
        for (int i = 0; i < 4; ++i)
#pragma unroll
            for (int j = 0; j < 4; ++j)
                acc[i][j] = __builtin_amdgcn_mfma_f32_16x16x32_bf16(af[i], bf[j], acc[i][j], 0, 0, 0);
    }
#pragma unroll
    for (int j = 0; j < 4; ++j) {
        int pl = wn * 64 + j * 16 + fm;
#pragma unroll
        for (int i = 0; i < 4; ++i)
#pragma unroll
            for (int r = 0; r < 4; ++r) {
                int nl = wm * 64 + i * 16 + quad * 4 + r;
                Tr[nl * 130 + pl] = f2bf(__expf(acc[i][j][r] * 0.0625f));
            }
    }
    __syncthreads();
#pragma unroll
    for (int i = 0; i < 8; ++i) {
        int f = i * 2048 + t * 8;
        int nl = f >> 7, pl = f & 127;
        short8 v = *(const short8*)(Tr + nl * 130 + pl);
        *(short8*)(ATT + ((size_t)(n0 + nl) * 16 + g) * 1024 + pl0 + pl) = v;
    }
}

// ---------------------------------------------------------------------------
// softmax: w[n,g,p] = max(pf,1e-6)*eatt, UNNORMALIZED (in-place in ATT).
// INV[n][g] = 1/sum_p w.  pf via MFMA with on-the-fly E, PD-precomputed parts.
// ---------------------------------------------------------------------------
__global__ __launch_bounds__(256)
void softmax_fused(const float* __restrict__ rois, const float4* __restrict__ PD,
                   const float* __restrict__ Wg_w, const float* __restrict__ Wg_b,
                   u16* __restrict__ ATT, float* __restrict__ INV,
                   const int* __restrict__ n1b_p, const int* __restrict__ n1p_p, int PT) {
    __shared__ __align__(16) u16 att_s[16 * 1032];
    __shared__ float redl[4][16];

    const int n = blockIdx.x, t = threadIdx.x;
    const int w = t >> 6, lane = t & 63;
    const int fm = lane & 15, quad = lane >> 4;
    const int n1b = *n1b_p, n1p = *n1p_p;
    const int hh = (n >= n1b) ? 1 : 0;
    const int p0 = hh ? n1p : 0;
    const int Ph = hh ? (PT - n1p) : n1p;   // 1024

    // stage eatt slice (coalesced)
#pragma unroll
    for (int i = 0; i < 8; ++i) {
        int e = i * 2048 + t * 8;
        int g = e >> 10, p = e & 1023;
        if (p < Ph) {
            short8 v = *(const short8*)(ATT + ((size_t)n * 16 + g) * 1024 + p);
            *(short8*)(att_s + g * 1032 + p) = v;
        }
    }

    // n-box (block-uniform)
    float xmin = rois[n * 5 + 1], ymin = rois[n * 5 + 2];
    float xmax = rois[n * 5 + 3], ymax = rois[n * 5 + 4];
    float bw = xmax - xmin + 1.0f, bh = ymax - ymin + 1.0f;
    float cx = 0.5f * (xmin + xmax), cy = 0.5f * (ymin + ymax);

    const int jA = quad >> 1, trig = quad & 1;
    // per-lane hoisted selections
    float cA   = (jA == 0) ? cx : cy;
    float invA = (jA == 0) ? (1.0f / bw) : (1.0f / bh);
    float lB   = (jA == 0) ? __logf(bw) : __logf(bh);

    // Wg b-fragments in registers; bias folded into acc init
    const int g_ = fm;
    short8 b1, b2;
    {
        const float* w1 = Wg_w + g_ * 64 + quad * 8;
        const float* w2 = Wg_w + g_ * 64 + 32 + quad * 8;
        unsigned* p1 = (unsigned*)&b1;
        unsigned* p2 = (unsigned*)&b2;
#pragma unroll
        for (int kk = 0; kk < 4; ++kk) {
            p1[kk] = pkbf(w1[2 * kk], w1[2 * kk + 1]);
            p2[kk] = pkbf(w2[2 * kk], w2[2 * kk + 1]);
        }
    }
    float wgb = Wg_b[g_];
    __syncthreads();

    const float inv_em[8] = {1.0f, 0.4216965034f, 0.1778279410f, 0.0749894209f,
                             0.0316227766f, 0.0133352143f, 0.0056234133f, 0.0023713737f};
    const int prange = Ph >> 2;              // p per wave (256)
    float ssum = 0.0f;

#pragma unroll 2
    for (int pt = 0; pt < 16; ++pt) {
        int pbase = w * prange + pt * 16;
        bool active = (pt * 16) < prange;
        if (active) {
            float4 pd = PD[p0 + pbase + fm];
            float pc = (jA == 0) ? pd.x : pd.y;
            float lp = (jA == 0) ? pd.z : pd.w;
            float posA = __logf(fmaxf(fabsf(cA - pc) * invA, 0.001f));
            float posB = lp - lB;
            float base1 = 100.0f * posA, base2 = 100.0f * posB;
            float e1[8], e2[8];
#pragma unroll
            for (int k = 0; k < 8; ++k) {
                float a1v = base1 * inv_em[k];
                float a2v = base2 * inv_em[k];
                e1[k] = trig ? __cosf(a1v) : __sinf(a1v);
                e2[k] = trig ? __cosf(a2v) : __sinf(a2v);
            }
            short8 a1, a2;
            unsigned* pa1 = (unsigned*)&a1;
            unsigned* pa2 = (unsigned*)&a2;
#pragma unroll
            for (int kk = 0; kk < 4; ++kk) {
                pa1[kk] = pkbf(e1[2 * kk], e1[2 * kk + 1]);
                pa2[kk] = pkbf(e2[2 * kk], e2[2 * kk + 1]);
            }
            float4v acc = {wgb, wgb, wgb, wgb};
            acc = __builtin_amdgcn_mfma_f32_16x16x32_bf16(a1, b1, acc, 0, 0, 0);
            acc = __builtin_amdgcn_mfma_f32_16x16x32_bf16(a2, b2, acc, 0, 0, 0);

            u16* slot = att_s + g_ * 1032 + pbase + quad * 4;
            ushort4 ea = *(const ushort4*)slot;
            float w0 = fmaxf(acc[0], 1e-6f) * bf2f(ea.x);
            float w1v = fmaxf(acc[1], 1e-6f) * bf2f(ea.y);
            float w2v = fmaxf(acc[2], 1e-6f) * bf2f(ea.z);
            float w3v = fmaxf(acc[3], 1e-6f) * bf2f(ea.w);
            ssum += (w0 + w1v) + (w2v + w3v);
            uint2 wp; wp.x = pkbf(w0, w1v); wp.y = pkbf(w2v, w3v);
            *(uint2*)slot = wp;
        }
    }

    ssum += __shfl_xor(ssum, 16, 64);
    ssum += __shfl_xor(ssum, 32, 64);
    if (lane < 16) redl[w][lane] = ssum;
    __syncthreads();
    if (t < 16)
        INV[(size_t)n * 16 + t] = 1.0f / (redl[0][t] + redl[1][t] + redl[2][t] + redl[3][t]);

    // copy unnormalized w back to global (coalesced)
#pragma unroll
    for (int i = 0; i < 8; ++i) {
        int e = i * 2048 + t * 8;
        int g = e >> 10, p = e & 1023;
        if (p < Ph) {
            short8 v = *(const short8*)(att_s + g * 1032 + p);
            *(short8*)(ATT + ((size_t)n * 16 + g) * 1024 + p) = v;
        }
    }
}

// ---------------------------------------------------------------------------
// rel: OUT[n, g*64+o] = (sum_p w[n,g,p]*PVt[g*64+o, p0+p]) * INV[n,g] + conv_b
// ---------------------------------------------------------------------------
__global__ __launch_bounds__(256)
void rel_mfma(const u16* __restrict__ SM, const u16* __restrict__ PVt,
              const float* __restrict__ conv_b, const float* __restrict__ INV,
              float* __restrict__ OUT, const int* __restrict__ n1b_p,
              const int* __restrict__ n1p_p, int PT) {
    __shared__ __align__(16) u16 As[128 * 64];
    __shared__ __align__(16) u16 Bs[64 * 64];

    const int n0 = blockIdx.x * 128, g = blockIdx.y;
    const int n1b = *n1b_p, n1p = *n1p_p;
    const int hh = (n0 >= n1b) ? 1 : 0;
    const int p0 = hh ? n1p : 0;
    const int Ph = hh ? (PT - n1p) : n1p;
    const int t = threadIdx.x;
    const int w = t >> 6, lane = t & 63;
    const int wm = w >> 1, wn = w & 1;
    const int lr = lane >> 3, lc = lane & 7, gch = lc ^ lr;
    const int fm = lane & 15, quad = lane >> 4;

    float4v zero4 = {0.f, 0.f, 0.f, 0.f};
    float4v acc[4][2];
#pragma unroll
    for (int i = 0; i < 4; ++i) { acc[i][0] = zero4; acc[i][1] = zero4; }

    for (int k0 = 0; k0 < Ph; k0 += 64) {
#pragma unroll
        for (int i = 0; i < 4; ++i) {
            int row = w * 32 + i * 8 + lr;
            dma16(SM + ((size_t)(n0 + row) * 16 + g) * 1024 + k0 + gch * 8,
                  As + (w * 32 + i * 8) * 64 + lane * 8);
        }
#pragma unroll
        for (int i = 0; i < 2; ++i) {
            int row = w * 16 + i * 8 + lr;
            dma16(PVt + (size_t)(g * 64 + row) * PT + p0 + k0 + gch * 8,
                  Bs + (w * 16 + i * 8) * 64 + lane * 8);
        }
        __syncthreads();
#pragma unroll
        for (int ks = 0; ks < 2; ++ks) {
            int c = ks * 4 + quad;
            short8 af[4], bf[2];
#pragma unroll
            for (int i = 0; i < 4; ++i) {
                int ra = wm * 64 + i * 16 + fm;
                af[i] = *(const short8*)(As + ra * 64 + ((c ^ (ra & 7)) * 8));
            }
#pragma unroll
            for (int j = 0; j < 2; ++j) {
                int rb = wn * 32 + j * 16 + fm;
                bf[j] = *(const short8*)(Bs + rb * 64 + ((c ^ (rb & 7)) * 8));
            }
#pragma unroll
            for (int i = 0; i < 4; ++i)
#pragma unroll
                for (int j = 0; j < 2; ++j)
                    acc[i][j] = __builtin_amdgcn_mfma_f32_16x16x32_bf16(af[i], bf[j], acc[i][j], 0, 0, 0);
        }
        __syncthreads();
    }
    float bb[2];
    bb[0] = conv_b[g * 64 + wn * 32 + fm];
    bb[1] = conv_b[g * 64 + wn * 32 + 16 + fm];
#pragma unroll
    for (int i = 0; i < 4; ++i)
#pragma unroll
        for (int r = 0; r < 4; ++r) {
            int nn = n0 + wm * 64 + i * 16 + quad * 4 + r;
            float iv = INV[(size_t)nn * 16 + g];
#pragma unroll
            for (int j = 0; j < 2; ++j) {
                int o = wn * 32 + j * 16 + fm;
                OUT[(size_t)nn * 1024 + g * 64 + o] = acc[i][j][r] * iv + bb[j];
            }
        }
}

extern "C" void kernel_launch(void* const* d_in, const int* in_sizes, int n_in,
                              void* d_out, int out_size, void* d_ws, size_t ws_size,
                              hipStream_t stream) {
    const float* rois   = (const float*)d_in[0];
    const float* prois  = (const float*)d_in[1];
    const float* bfeat  = (const float*)d_in[2];
    const float* pfeat  = (const float*)d_in[3];
    const float* Wg_w   = (const float*)d_in[4];
    const float* Wg_b   = (const float*)d_in[5];
    const float* Wq_w   = (const float*)d_in[6];
    const float* Wq_b   = (const float*)d_in[7];
    const float* Wk_w   = (const float*)d_in[8];
    const float* Wk_b   = (const float*)d_in[9];
    const float* conv_w = (const float*)d_in[10];
    const float* conv_b = (const float*)d_in[11];
    const int*   n1b    = (const int*)d_in[12];
    const int*   n1p    = (const int*)d_in[13];

    const int NT = in_sizes[2] / 1024;  // 2048
    const int PT = in_sizes[3] / 1024;  // 2048

    // ws layout (u16 units); conversion buffers alias ATT (consumed by proj
    // before att_mfma overwrites ATT).
    u16* ATT = (u16*)d_ws;                          // [NT][16][1024]
    u16* Qb  = ATT + (size_t)NT * 16 * 1024;        // [NT][1024]
    u16* Kb  = Qb + (size_t)NT * 1024;              // [PT][1024]
    u16* PVt = Kb + (size_t)PT * 1024;              // [1024][PT]
    float* INVp = (float*)(PVt + (size_t)1024 * PT);   // [NT][16]
    float4* PD  = (float4*)(INVp + (size_t)NT * 16);   // [PT]
    u16* Ab  = ATT;
    u16* Pb  = Ab + (size_t)NT * 1024;
    u16* Wqb = Pb + (size_t)PT * 1024;
    u16* Wkb = Wqb + 1024 * 1024;
    u16* Cwb = Wkb + 1024 * 1024;

    dim3 blk(256);
    int nf4 = NT * 1024 / 4, pf4 = PT * 1024 / 4, wf4 = 1024 * 1024 / 4;
    int tot = nf4 + pf4 + 3 * wf4 + PT;
    cvt_all<<<dim3((tot + 255) / 256), blk, 0, stream>>>(
        bfeat, pfeat, Wq_w, Wk_w, conv_w, prois, Ab, Pb, Wqb, Wkb, Cwb, PD,
        nf4, pf4, wf4, PT);

    proj_mfma<<<dim3(8, NT / 128, 3), blk, 0, stream>>>(Ab, Pb, Wqb, Wkb, Cwb,
                                                        Wq_b, Wk_b, Qb, Kb, PVt, PT);
    att_mfma<<<dim3(PT / 128, NT / 128, 16), blk, 0, stream>>>(Qb, Kb, ATT, n1b, n1p, PT);
    softmax_fused<<<dim3(NT), blk, 0, stream>>>(rois, PD, Wg_w, Wg_b, ATT, INVp, n1b, n1p, PT);
    rel_mfma<<<dim3(NT / 128, 16), blk, 0, stream>>>(ATT, PVt, conv_b, INVp,
                                                     (float*)d_out, n1b, n1p, PT);
}

// Round 6
// 212.100 us; speedup vs baseline: 2.8175x; 1.0622x over previous
//
#include <hip/hip_runtime.h>

typedef unsigned short u16;
using short8  = __attribute__((ext_vector_type(8))) short;
using float4v = __attribute__((ext_vector_type(4))) float;

__device__ __forceinline__ u16 f2bf(float f) {
    union { float f; unsigned u; } v; v.f = f;
    unsigned r = (v.u + 0x7fff + ((v.u >> 16) & 1)) >> 16;
    return (u16)r;
}
__device__ __forceinline__ float bf2f(u16 h) {
    union { unsigned u; float f; } v; v.u = ((unsigned)h) << 16; return v.f;
}
// HW packed f32x2 -> bf16x2 (lo in low 16 bits). CDNA3+/gfx950.
__device__ __forceinline__ unsigned pkbf(float lo, float hi) {
    unsigned d;
    asm("v_cvt_pk_bf16_f32 %0, %1, %2" : "=v"(d) : "v"(lo), "v"(hi));
    return d;
}
// sin(2*pi*r): v_fract then hardware v_sin (input in revolutions).
__device__ __forceinline__ float sin_rev(float r) {
    float f, s;
    asm("v_fract_f32 %0, %1" : "=v"(f) : "v"(r));
    asm("v_sin_f32 %0, %1" : "=v"(s) : "v"(f));
    return s;
}
__device__ __forceinline__ void dma16(const void* g, void* l) {
    __builtin_amdgcn_global_load_lds((const __attribute__((address_space(1))) void*)g,
                                     (__attribute__((address_space(3))) void*)l, 16, 0, 0);
}

// ---------------------------------------------------------------------------
// merged f32 -> bf16 bulk convert for five tensors + PD precompute
// PD[p] = (pcx, pcy, log(pw), log(ph))
// ---------------------------------------------------------------------------
__device__ __forceinline__ void cvt4(const float* __restrict__ s, u16* __restrict__ o, int i) {
    float4 v = ((const float4*)s)[i];
    uint2 r; r.x = pkbf(v.x, v.y); r.y = pkbf(v.z, v.w);
    ((uint2*)o)[i] = r;
}

__global__ __launch_bounds__(256)
void cvt_all(const float* __restrict__ s0, const float* __restrict__ s1,
             const float* __restrict__ s2, const float* __restrict__ s3,
             const float* __restrict__ s4, const float* __restrict__ prois,
             u16* __restrict__ o0, u16* __restrict__ o1, u16* __restrict__ o2,
             u16* __restrict__ o3, u16* __restrict__ o4, float4* __restrict__ PD,
             int na4, int nb4, int nw4, int PT) {
    int i = blockIdx.x * 256 + threadIdx.x;
    if (i < na4) { cvt4(s0, o0, i); return; }
    i -= na4;
    if (i < nb4) { cvt4(s1, o1, i); return; }
    i -= nb4;
    if (i < nw4) { cvt4(s2, o2, i); return; }
    i -= nw4;
    if (i < nw4) { cvt4(s3, o3, i); return; }
    i -= nw4;
    if (i < nw4) { cvt4(s4, o4, i); return; }
    i -= nw4;
    if (i < PT) {
        const float* pr = prois + (size_t)i * 5;
        float pxmin = pr[1], pymin = pr[2], pxmax = pr[3], pymax = pr[4];
        PD[i] = make_float4(0.5f * (pxmin + pxmax), 0.5f * (pymin + pymax),
                            __logf(pxmax - pxmin + 1.0f), __logf(pymax - pymin + 1.0f));
    }
}

// ---------------------------------------------------------------------------
// proj: C[m,j] = sum_k A[m,k]*W[j,k] (+bias). z=0: Q, z=1: K, z=2: PV->PVt.
// ---------------------------------------------------------------------------
__global__ __launch_bounds__(256)
void proj_mfma(const u16* __restrict__ Ab, const u16* __restrict__ Pb,
               const u16* __restrict__ Wqb, const u16* __restrict__ Wkb,
               const u16* __restrict__ Cwb, const float* __restrict__ bq,
               const float* __restrict__ bk, u16* __restrict__ Qb,
               u16* __restrict__ Kb, u16* __restrict__ PVt, int PT) {
    __shared__ __align__(16) u16 As[128 * 64];
    __shared__ __align__(16) u16 Ws[128 * 64];
    __shared__ __align__(16) u16 Tr[128 * 130];

    const int z = blockIdx.z;
    const int m0 = blockIdx.y * 128, j0 = blockIdx.x * 128;
    const u16* A = (z == 0) ? Ab : Pb;
    const u16* W = (z == 0) ? Wqb : (z == 1 ? Wkb : Cwb);
    const int t = threadIdx.x;
    const int w = t >> 6, lane = t & 63;
    const int wm = w >> 1, wn = w & 1;
    const int lr = lane >> 3, lc = lane & 7, gch = lc ^ lr;
    const int fm = lane & 15, quad = lane >> 4;

    float4v zero4 = {0.f, 0.f, 0.f, 0.f};
    float4v acc[4][4];
#pragma unroll
    for (int i = 0; i < 4; ++i)
#pragma unroll
        for (int j = 0; j < 4; ++j) acc[i][j] = zero4;

    for (int k0 = 0; k0 < 1024; k0 += 64) {
#pragma unroll
        for (int i = 0; i < 4; ++i) {
            int row = w * 32 + i * 8 + lr;
            dma16(A + (size_t)(m0 + row) * 1024 + k0 + gch * 8,
                  As + (w * 32 + i * 8) * 64 + lane * 8);
            dma16(W + (size_t)(j0 + row) * 1024 + k0 + gch * 8,
                  Ws + (w * 32 + i * 8) * 64 + lane * 8);
        }
        __syncthreads();
#pragma unroll
        for (int ks = 0; ks < 2; ++ks) {
            int c = ks * 4 + quad;
            short8 af[4], bf[4];
#pragma unroll
            for (int i = 0; i < 4; ++i) {
                int ra = wm * 64 + i * 16 + fm;
                af[i] = *(const short8*)(As + ra * 64 + ((c ^ (ra & 7)) * 8));
                int rb = wn * 64 + i * 16 + fm;
                bf[i] = *(const short8*)(Ws + rb * 64 + ((c ^ (rb & 7)) * 8));
            }
#pragma unroll
            for (int i = 0; i < 4; ++i)
#pragma unroll
                for (int j = 0; j < 4; ++j)
                    acc[i][j] = __builtin_amdgcn_mfma_f32_16x16x32_bf16(af[i], bf[j], acc[i][j], 0, 0, 0);
        }
        __syncthreads();
    }

    if (z < 2) {
        u16* O = z ? Kb : Qb;
        const float* bias = z ? bk : bq;
#pragma unroll
        for (int j = 0; j < 4; ++j) {
            int jj = j0 + wn * 64 + j * 16 + fm;
            float bb = bias[jj];
#pragma unroll
            for (int i = 0; i < 4; ++i)
#pragma unroll
                for (int r = 0; r < 4; ++r) {
                    int m = m0 + wm * 64 + i * 16 + quad * 4 + r;
                    O[(size_t)m * 1024 + jj] = f2bf(acc[i][j][r] + bb);
                }
        }
    } else {
#pragma unroll
        for (int j = 0; j < 4; ++j) {
            int jl = wn * 64 + j * 16 + fm;
#pragma unroll
            for (int i = 0; i < 4; ++i) {
                int mlb = wm * 64 + i * 16 + quad * 4;
                uint2 pk;
                pk.x = pkbf(acc[i][j][0], acc[i][j][1]);
                pk.y = pkbf(acc[i][j][2], acc[i][j][3]);
                *(uint2*)(Tr + jl * 130 + mlb) = pk;
            }
        }
        __syncthreads();
#pragma unroll
        for (int i = 0; i < 8; ++i) {
            int f = i * 2048 + t * 8;
            int jl = f >> 7, ml = f & 127;
            short8 v = *(const short8*)(Tr + jl * 130 + ml);
            *(short8*)(PVt + (size_t)(j0 + jl) * PT + m0 + ml) = v;
        }
    }
}

// ---------------------------------------------------------------------------
// att: ATT[n][g][p] = exp((1/16) sum_d Q*K)  -- exp folded in, bf16 out.
// ---------------------------------------------------------------------------
__global__ __launch_bounds__(256)
void att_mfma(const u16* __restrict__ Qb, const u16* __restrict__ Kb,
              u16* __restrict__ ATT, const int* __restrict__ n1b_p,
              const int* __restrict__ n1p_p, int PT) {
    __shared__ __align__(16) u16 Qs[128 * 64];
    __shared__ __align__(16) u16 Ks[128 * 64];
    __shared__ __align__(16) u16 Tr[128 * 130];

    const int g = blockIdx.z;
    const int n0 = blockIdx.y * 128, pl0 = blockIdx.x * 128;
    const int n1b = *n1b_p, n1p = *n1p_p;
    const int hh = (n0 >= n1b) ? 1 : 0;
    const int p0 = hh ? n1p : 0;
    const int Ph = hh ? (PT - n1p) : n1p;
    if (pl0 >= Ph) return;
    const int t = threadIdx.x;
    const int w = t >> 6, lane = t & 63;
    const int wm = w >> 1, wn = w & 1;
    const int lr = lane >> 3, lc = lane & 7, gch = lc ^ lr;
    const int fm = lane & 15, quad = lane >> 4;

    float4v zero4 = {0.f, 0.f, 0.f, 0.f};
    float4v acc[4][4];
#pragma unroll
    for (int i = 0; i < 4; ++i)
#pragma unroll
        for (int j = 0; j < 4; ++j) acc[i][j] = zero4;

#pragma unroll
    for (int i = 0; i < 4; ++i) {
        int row = w * 32 + i * 8 + lr;
        dma16(Qb + (size_t)(n0 + row) * 1024 + g * 64 + gch * 8,
              Qs + (w * 32 + i * 8) * 64 + lane * 8);
        dma16(Kb + (size_t)(p0 + pl0 + row) * 1024 + g * 64 + gch * 8,
              Ks + (w * 32 + i * 8) * 64 + lane * 8);
    }
    __syncthreads();
#pragma unroll
    for (int ks = 0; ks < 2; ++ks) {
        int c = ks * 4 + quad;
        short8 af[4], bf[4];
#pragma unroll
        for (int i = 0; i < 4; ++i) {
            int ra = wm * 64 + i * 16 + fm;
            af[i] = *(const short8*)(Qs + ra * 64 + ((c ^ (ra & 7)) * 8));
            int rb = wn * 64 + i * 16 + fm;
            bf[i] = *(const short8*)(Ks + rb * 64 + ((c ^ (rb & 7)) * 8));
        }
#pragma unroll
        for (int i = 0; i < 4; ++i)
#pragma unroll
            for (int j = 0; j < 4; ++j)
                acc[i][j] = __builtin_amdgcn_mfma_f32_16x16x32_bf16(af[i], bf[j], acc[i][j], 0, 0, 0);
    }
#pragma unroll
    for (int j = 0; j < 4; ++j) {
        int pl = wn * 64 + j * 16 + fm;
#pragma unroll
        for (int i = 0; i < 4; ++i)
#pragma unroll
            for (int r = 0; r < 4; ++r) {
                int nl = wm * 64 + i * 16 + quad * 4 + r;
                Tr[nl * 130 + pl] = f2bf(__expf(acc[i][j][r] * 0.0625f));
            }
    }
    __syncthreads();
#pragma unroll
    for (int i = 0; i < 8; ++i) {
        int f = i * 2048 + t * 8;
        int nl = f >> 7, pl = f & 127;
        short8 v = *(const short8*)(Tr + nl * 130 + pl);
        *(short8*)(ATT + ((size_t)(n0 + nl) * 16 + g) * 1024 + pl0 + pl) = v;
    }
}

// ---------------------------------------------------------------------------
// softmax: w[n,g,p] = max(pf,1e-6)*eatt, UNNORMALIZED, in-place in ATT via
// DIRECT global access (D-layout lane (fm,quad) owns a contiguous 8B of the
// [n][g][p] row g=fm). No LDS staging. INV[n][g] = 1/sum_p w.
// Trig: sin-only via revolutions identity (cos(x)=sin(x/2pi+0.25)).
// ---------------------------------------------------------------------------
__global__ __launch_bounds__(256)
void softmax_fused(const float* __restrict__ rois, const float4* __restrict__ PD,
                   const float* __restrict__ Wg_w, const float* __restrict__ Wg_b,
                   u16* __restrict__ ATT, float* __restrict__ INV,
                   const int* __restrict__ n1b_p, const int* __restrict__ n1p_p, int PT) {
    __shared__ float redl[4][16];

    const int n = blockIdx.x, t = threadIdx.x;
    const int w = t >> 6, lane = t & 63;
    const int fm = lane & 15, quad = lane >> 4;
    const int n1b = *n1b_p, n1p = *n1p_p;
    const int hh = (n >= n1b) ? 1 : 0;
    const int p0 = hh ? n1p : 0;
    const int Ph = hh ? (PT - n1p) : n1p;   // 1024

    // n-box (block-uniform)
    float xmin = rois[n * 5 + 1], ymin = rois[n * 5 + 2];
    float xmax = rois[n * 5 + 3], ymax = rois[n * 5 + 4];
    float bw = xmax - xmin + 1.0f, bh = ymax - ymin + 1.0f;
    float cx = 0.5f * (xmin + xmax), cy = 0.5f * (ymin + ymax);

    const int jA = quad >> 1, trig = quad & 1;
    float cA   = (jA == 0) ? cx : cy;
    float invA = (jA == 0) ? (1.0f / bw) : (1.0f / bh);
    float lB   = (jA == 0) ? __logf(bw) : __logf(bh);
    float toff = trig ? 0.25f : 0.0f;

    // Wg b-fragments in registers; bias folded into acc init
    const int g_ = fm;
    short8 b1, b2;
    {
        const float* w1 = Wg_w + g_ * 64 + quad * 8;
        const float* w2 = Wg_w + g_ * 64 + 32 + quad * 8;
        unsigned* p1 = (unsigned*)&b1;
        unsigned* p2 = (unsigned*)&b2;
#pragma unroll
        for (int kk = 0; kk < 4; ++kk) {
            p1[kk] = pkbf(w1[2 * kk], w1[2 * kk + 1]);
            p2[kk] = pkbf(w2[2 * kk], w2[2 * kk + 1]);
        }
    }
    float wgb = Wg_b[g_];

    const float inv_em[8] = {1.0f, 0.4216965034f, 0.1778279410f, 0.0749894209f,
                             0.0316227766f, 0.0133352143f, 0.0056234133f, 0.0023713737f};
    const float REV = 15.91549431f;  // 100 / (2*pi)
    const int prange = Ph >> 2;      // p per wave (256)
    float ssum = 0.0f;
    u16* rowp = ATT + ((size_t)n * 16 + g_) * 1024;  // row for g = fm

#pragma unroll 2
    for (int pt = 0; pt < 16; ++pt) {
        int pbase = w * prange + pt * 16;
        if ((pt * 16) < prange) {
            float4 pd = PD[p0 + pbase + fm];
            float pc = (jA == 0) ? pd.x : pd.y;
            float lp = (jA == 0) ? pd.z : pd.w;
            float posA = __logf(fmaxf(fabsf(cA - pc) * invA, 0.001f));
            float posB = lp - lB;
            float br1 = posA * REV, br2 = posB * REV;
            float e1[8], e2[8];
#pragma unroll
            for (int k = 0; k < 8; ++k) {
                e1[k] = sin_rev(fmaf(br1, inv_em[k], toff));
                e2[k] = sin_rev(fmaf(br2, inv_em[k], toff));
            }
            short8 a1, a2;
            unsigned* pa1 = (unsigned*)&a1;
            unsigned* pa2 = (unsigned*)&a2;
#pragma unroll
            for (int kk = 0; kk < 4; ++kk) {
                pa1[kk] = pkbf(e1[2 * kk], e1[2 * kk + 1]);
                pa2[kk] = pkbf(e2[2 * kk], e2[2 * kk + 1]);
            }
            float4v acc = {wgb, wgb, wgb, wgb};
            acc = __builtin_amdgcn_mfma_f32_16x16x32_bf16(a1, b1, acc, 0, 0, 0);
            acc = __builtin_amdgcn_mfma_f32_16x16x32_bf16(a2, b2, acc, 0, 0, 0);

            u16* slot = rowp + pbase + quad * 4;
            ushort4 ea = *(const ushort4*)slot;
            float w0  = fmaxf(acc[0], 1e-6f) * bf2f(ea.x);
            float w1v = fmaxf(acc[1], 1e-6f) * bf2f(ea.y);
            float w2v = fmaxf(acc[2], 1e-6f) * bf2f(ea.z);
            float w3v = fmaxf(acc[3], 1e-6f) * bf2f(ea.w);
            ssum += (w0 + w1v) + (w2v + w3v);
            uint2 wp; wp.x = pkbf(w0, w1v); wp.y = pkbf(w2v, w3v);
            *(uint2*)slot = wp;
        }
    }

    ssum += __shfl_xor(ssum, 16, 64);
    ssum += __shfl_xor(ssum, 32, 64);
    if (lane < 16) redl[w][lane] = ssum;
    __syncthreads();
    if (t < 16)
        INV[(size_t)n * 16 + t] = 1.0f / (redl[0][t] + redl[1][t] + redl[2][t] + redl[3][t]);
}

// ---------------------------------------------------------------------------
// rel: OUT[n, g*64+o] = (sum_p w[n,g,p]*PVt[g*64+o, p0+p]) * INV[n,g] + conv_b
// ---------------------------------------------------------------------------
__global__ __launch_bounds__(256)
void rel_mfma(const u16* __restrict__ SM, const u16* __restrict__ PVt,
              const float* __restrict__ conv_b, const float* __restrict__ INV,
              float* __restrict__ OUT, const int* __restrict__ n1b_p,
              const int* __restrict__ n1p_p, int PT) {
    __shared__ __align__(16) u16 As[128 * 64];
    __shared__ __align__(16) u16 Bs[64 * 64];

    const int n0 = blockIdx.x * 128, g = blockIdx.y;
    const int n1b = *n1b_p, n1p = *n1p_p;
    const int hh = (n0 >= n1b) ? 1 : 0;
    const int p0 = hh ? n1p : 0;
    const int Ph = hh ? (PT - n1p) : n1p;
    const int t = threadIdx.x;
    const int w = t >> 6, lane = t & 63;
    const int wm = w >> 1, wn = w & 1;
    const int lr = lane >> 3, lc = lane & 7, gch = lc ^ lr;
    const int fm = lane & 15, quad = lane >> 4;

    float4v zero4 = {0.f, 0.f, 0.f, 0.f};
    float4v acc[4][2];
#pragma unroll
    for (int i = 0; i < 4; ++i) { acc[i][0] = zero4; acc[i][1] = zero4; }

    for (int k0 = 0; k0 < Ph; k0 += 64) {
#pragma unroll
        for (int i = 0; i < 4; ++i) {
            int row = w * 32 + i * 8 + lr;
            dma16(SM + ((size_t)(n0 + row) * 16 + g) * 1024 + k0 + gch * 8,
                  As + (w * 32 + i * 8) * 64 + lane * 8);
        }
#pragma unroll
        for (int i = 0; i < 2; ++i) {
            int row = w * 16 + i * 8 + lr;
            dma16(PVt + (size_t)(g * 64 + row) * PT + p0 + k0 + gch * 8,
                  Bs + (w * 16 + i * 8) * 64 + lane * 8);
        }
        __syncthreads();
#pragma unroll
        for (int ks = 0; ks < 2; ++ks) {
            int c = ks * 4 + quad;
            short8 af[4], bf[2];
#pragma unroll
            for (int i = 0; i < 4; ++i) {
                int ra = wm * 64 + i * 16 + fm;
                af[i] = *(const short8*)(As + ra * 64 + ((c ^ (ra & 7)) * 8));
            }
#pragma unroll
            for (int j = 0; j < 2; ++j) {
                int rb = wn * 32 + j * 16 + fm;
                bf[j] = *(const short8*)(Bs + rb * 64 + ((c ^ (rb & 7)) * 8));
            }
#pragma unroll
            for (int i = 0; i < 4; ++i)
#pragma unroll
                for (int j = 0; j < 2; ++j)
                    acc[i][j] = __builtin_amdgcn_mfma_f32_16x16x32_bf16(af[i], bf[j], acc[i][j], 0, 0, 0);
        }
        __syncthreads();
    }
    float bb[2];
    bb[0] = conv_b[g * 64 + wn * 32 + fm];
    bb[1] = conv_b[g * 64 + wn * 32 + 16 + fm];
#pragma unroll
    for (int i = 0; i < 4; ++i)
#pragma unroll
        for (int r = 0; r < 4; ++r) {
            int nn = n0 + wm * 64 + i * 16 + quad * 4 + r;
            float iv = INV[(size_t)nn * 16 + g];
#pragma unroll
            for (int j = 0; j < 2; ++j) {
                int o = wn * 32 + j * 16 + fm;
                OUT[(size_t)nn * 1024 + g * 64 + o] = acc[i][j][r] * iv + bb[j];
            }
        }
}

extern "C" void kernel_launch(void* const* d_in, const int* in_sizes, int n_in,
                              void* d_out, int out_size, void* d_ws, size_t ws_size,
                              hipStream_t stream) {
    const float* rois   = (const float*)d_in[0];
    const float* prois  = (const float*)d_in[1];
    const float* bfeat  = (const float*)d_in[2];
    const float* pfeat  = (const float*)d_in[3];
    const float* Wg_w   = (const float*)d_in[4];
    const float* Wg_b   = (const float*)d_in[5];
    const float* Wq_w   = (const float*)d_in[6];
    const float* Wq_b   = (const float*)d_in[7];
    const float* Wk_w   = (const float*)d_in[8];
    const float* Wk_b   = (const float*)d_in[9];
    const float* conv_w = (const float*)d_in[10];
    const float* conv_b = (const float*)d_in[11];
    const int*   n1b    = (const int*)d_in[12];
    const int*   n1p    = (const int*)d_in[13];

    const int NT = in_sizes[2] / 1024;  // 2048
    const int PT = in_sizes[3] / 1024;  // 2048

    // ws layout (u16 units); conversion buffers alias ATT (consumed by proj
    // before att_mfma overwrites ATT).
    u16* ATT = (u16*)d_ws;                          // [NT][16][1024]
    u16* Qb  = ATT + (size_t)NT * 16 * 1024;        // [NT][1024]
    u16* Kb  = Qb + (size_t)NT * 1024;              // [PT][1024]
    u16* PVt = Kb + (size_t)PT * 1024;              // [1024][PT]
    float* INVp = (float*)(PVt + (size_t)1024 * PT);   // [NT][16]
    float4* PD  = (float4*)(INVp + (size_t)NT * 16);   // [PT]
    u16* Ab  = ATT;
    u16* Pb  = Ab + (size_t)NT * 1024;
    u16* Wqb = Pb + (size_t)PT * 1024;
    u16* Wkb = Wqb + 1024 * 1024;
    u16* Cwb = Wkb + 1024 * 1024;

    dim3 blk(256);
    int nf4 = NT * 1024 / 4, pf4 = PT * 1024 / 4, wf4 = 1024 * 1024 / 4;
    int tot = nf4 + pf4 + 3 * wf4 + PT;
    cvt_all<<<dim3((tot + 255) / 256), blk, 0, stream>>>(
        bfeat, pfeat, Wq_w, Wk_w, conv_w, prois, Ab, Pb, Wqb, Wkb, Cwb, PD,
        nf4, pf4, wf4, PT);

    proj_mfma<<<dim3(8, NT / 128, 3), blk, 0, stream>>>(Ab, Pb, Wqb, Wkb, Cwb,
                                                        Wq_b, Wk_b, Qb, Kb, PVt, PT);
    att_mfma<<<dim3(PT / 128, NT / 128, 16), blk, 0, stream>>>(Qb, Kb, ATT, n1b, n1p, PT);
    softmax_fused<<<dim3(NT), blk, 0, stream>>>(rois, PD, Wg_w, Wg_b, ATT, INVp, n1b, n1p, PT);
    rel_mfma<<<dim3(NT / 128, 16), blk, 0, stream>>>(ATT, PVt, conv_b, INVp,
                                                     (float*)d_out, n1b, n1p, PT);
}

// Round 7
// 202.792 us; speedup vs baseline: 2.9468x; 1.0459x over previous
//
#include <hip/hip_runtime.h>

typedef unsigned short u16;
using short8  = __attribute__((ext_vector_type(8))) short;
using float4v = __attribute__((ext_vector_type(4))) float;

__device__ __forceinline__ u16 f2bf(float f) {
    union { float f; unsigned u; } v; v.f = f;
    unsigned r = (v.u + 0x7fff + ((v.u >> 16) & 1)) >> 16;
    return (u16)r;
}
__device__ __forceinline__ float bf2f(u16 h) {
    union { unsigned u; float f; } v; v.u = ((unsigned)h) << 16; return v.f;
}
// HW packed f32x2 -> bf16x2 (lo in low 16 bits). CDNA3+/gfx950.
__device__ __forceinline__ unsigned pkbf(float lo, float hi) {
    unsigned d;
    asm("v_cvt_pk_bf16_f32 %0, %1, %2" : "=v"(d) : "v"(lo), "v"(hi));
    return d;
}
// sin(2*pi*r): v_fract then hardware v_sin (input in revolutions).
__device__ __forceinline__ float sin_rev(float r) {
    float f, s;
    asm("v_fract_f32 %0, %1" : "=v"(f) : "v"(r));
    asm("v_sin_f32 %0, %1" : "=v"(s) : "v"(f));
    return s;
}
__device__ __forceinline__ void dma16(const void* g, void* l) {
    __builtin_amdgcn_global_load_lds((const __attribute__((address_space(1))) void*)g,
                                     (__attribute__((address_space(3))) void*)l, 16, 0, 0);
}

// ---------------------------------------------------------------------------
// merged f32 -> bf16 bulk convert for five tensors + PD precompute
// ---------------------------------------------------------------------------
__device__ __forceinline__ void cvt4(const float* __restrict__ s, u16* __restrict__ o, int i) {
    float4 v = ((const float4*)s)[i];
    uint2 r; r.x = pkbf(v.x, v.y); r.y = pkbf(v.z, v.w);
    ((uint2*)o)[i] = r;
}

__global__ __launch_bounds__(256)
void cvt_all(const float* __restrict__ s0, const float* __restrict__ s1,
             const float* __restrict__ s2, const float* __restrict__ s3,
             const float* __restrict__ s4, const float* __restrict__ prois,
             u16* __restrict__ o0, u16* __restrict__ o1, u16* __restrict__ o2,
             u16* __restrict__ o3, u16* __restrict__ o4, float4* __restrict__ PD,
             int na4, int nb4, int nw4, int PT) {
    int i = blockIdx.x * 256 + threadIdx.x;
    if (i < na4) { cvt4(s0, o0, i); return; }
    i -= na4;
    if (i < nb4) { cvt4(s1, o1, i); return; }
    i -= nb4;
    if (i < nw4) { cvt4(s2, o2, i); return; }
    i -= nw4;
    if (i < nw4) { cvt4(s3, o3, i); return; }
    i -= nw4;
    if (i < nw4) { cvt4(s4, o4, i); return; }
    i -= nw4;
    if (i < PT) {
        const float* pr = prois + (size_t)i * 5;
        float pxmin = pr[1], pymin = pr[2], pxmax = pr[3], pymax = pr[4];
        PD[i] = make_float4(0.5f * (pxmin + pxmax), 0.5f * (pymin + pymax),
                            __logf(pxmax - pxmin + 1.0f), __logf(pymax - pymin + 1.0f));
    }
}

// ---------------------------------------------------------------------------
// proj: C[m,j] = sum_k A[m,k]*W[j,k] (+bias). z=0: Q, z=1: K, z=2: PV->PVt.
// Tile 128m x 64j, BK=64, grid (16j,16m,3) = 768 blocks (3/CU).
// Coalesced epilogue via LDS transpose for ALL paths.
// ---------------------------------------------------------------------------
__global__ __launch_bounds__(256)
void proj_mfma(const u16* __restrict__ Ab, const u16* __restrict__ Pb,
               const u16* __restrict__ Wqb, const u16* __restrict__ Wkb,
               const u16* __restrict__ Cwb, const float* __restrict__ bq,
               const float* __restrict__ bk, u16* __restrict__ Qb,
               u16* __restrict__ Kb, u16* __restrict__ PVt, int PT) {
    __shared__ __align__(16) u16 As[128 * 64];   // 16 KB
    __shared__ __align__(16) u16 Ws[64 * 64];    //  8 KB
    __shared__ __align__(16) u16 Tr[128 * 68];   // 17 KB (z==2 views as [64][136])

    const int z = blockIdx.z;
    const int m0 = blockIdx.y * 128, j0 = blockIdx.x * 64;
    const u16* A = (z == 0) ? Ab : Pb;
    const u16* W = (z == 0) ? Wqb : (z == 1 ? Wkb : Cwb);
    const int t = threadIdx.x;
    const int w = t >> 6, lane = t & 63;
    const int wm = w >> 1, wn = w & 1;
    const int lr = lane >> 3, lc = lane & 7, gch = lc ^ lr;
    const int fm = lane & 15, quad = lane >> 4;

    float4v zero4 = {0.f, 0.f, 0.f, 0.f};
    float4v acc[4][2];
#pragma unroll
    for (int i = 0; i < 4; ++i) { acc[i][0] = zero4; acc[i][1] = zero4; }

    for (int k0 = 0; k0 < 1024; k0 += 64) {
#pragma unroll
        for (int i = 0; i < 4; ++i) {
            int row = w * 32 + i * 8 + lr;
            dma16(A + (size_t)(m0 + row) * 1024 + k0 + gch * 8,
                  As + (w * 32 + i * 8) * 64 + lane * 8);
        }
#pragma unroll
        for (int i = 0; i < 2; ++i) {
            int row = w * 16 + i * 8 + lr;
            dma16(W + (size_t)(j0 + row) * 1024 + k0 + gch * 8,
                  Ws + (w * 16 + i * 8) * 64 + lane * 8);
        }
        __syncthreads();
#pragma unroll
        for (int ks = 0; ks < 2; ++ks) {
            int c = ks * 4 + quad;
            short8 af[4], bf[2];
#pragma unroll
            for (int i = 0; i < 4; ++i) {
                int ra = wm * 64 + i * 16 + fm;
                af[i] = *(const short8*)(As + ra * 64 + ((c ^ (ra & 7)) * 8));
            }
#pragma unroll
            for (int j = 0; j < 2; ++j) {
                int rb = wn * 32 + j * 16 + fm;
                bf[j] = *(const short8*)(Ws + rb * 64 + ((c ^ (rb & 7)) * 8));
            }
#pragma unroll
            for (int i = 0; i < 4; ++i)
#pragma unroll
                for (int j = 0; j < 2; ++j)
                    acc[i][j] = __builtin_amdgcn_mfma_f32_16x16x32_bf16(af[i], bf[j], acc[i][j], 0, 0, 0);
        }
        __syncthreads();
    }

    if (z < 2) {
        u16* O = z ? Kb : Qb;
        const float* bias = z ? bk : bq;
        // Tr as [ml 128][jl 64] stride 68
#pragma unroll
        for (int j = 0; j < 2; ++j) {
            int jl = wn * 32 + j * 16 + fm;
            float bb = bias[j0 + jl];
#pragma unroll
            for (int i = 0; i < 4; ++i) {
                int mlb = wm * 64 + i * 16 + quad * 4;
#pragma unroll
                for (int r = 0; r < 4; ++r)
                    Tr[(mlb + r) * 68 + jl] = f2bf(acc[i][j][r] + bb);
            }
        }
        __syncthreads();
#pragma unroll
        for (int i2 = 0; i2 < 4; ++i2) {
            int f = i2 * 2048 + t * 8;
            int ml = f >> 6, jl = f & 63;
            union { uint2 u2[2]; short8 s8; } uu;
            uu.u2[0] = *(const uint2*)(Tr + ml * 68 + jl);
            uu.u2[1] = *(const uint2*)(Tr + ml * 68 + jl + 4);
            *(short8*)(O + (size_t)(m0 + ml) * 1024 + j0 + jl) = uu.s8;
        }
    } else {
        // Tr as [jl 64][ml 128] stride 136
#pragma unroll
        for (int j = 0; j < 2; ++j) {
            int jl = wn * 32 + j * 16 + fm;
#pragma unroll
            for (int i = 0; i < 4; ++i) {
                int mlb = wm * 64 + i * 16 + quad * 4;
                uint2 pk;
                pk.x = pkbf(acc[i][j][0], acc[i][j][1]);
                pk.y = pkbf(acc[i][j][2], acc[i][j][3]);
                *(uint2*)(Tr + jl * 136 + mlb) = pk;
            }
        }
        __syncthreads();
#pragma unroll
        for (int i2 = 0; i2 < 4; ++i2) {
            int f = i2 * 2048 + t * 8;
            int jl = f >> 7, ml = f & 127;
            union { uint2 u2[2]; short8 s8; } uu;
            uu.u2[0] = *(const uint2*)(Tr + jl * 136 + ml);
            uu.u2[1] = *(const uint2*)(Tr + jl * 136 + ml + 4);
            *(short8*)(PVt + (size_t)(j0 + jl) * PT + m0 + ml) = uu.s8;
        }
    }
}

// ---------------------------------------------------------------------------
// att: ATT[n][g][p] = exp((1/16) sum_d Q*K)  -- exp folded in, bf16 out.
// ---------------------------------------------------------------------------
__global__ __launch_bounds__(256)
void att_mfma(const u16* __restrict__ Qb, const u16* __restrict__ Kb,
              u16* __restrict__ ATT, const int* __restrict__ n1b_p,
              const int* __restrict__ n1p_p, int PT) {
    __shared__ __align__(16) u16 Qs[128 * 64];
    __shared__ __align__(16) u16 Ks[128 * 64];
    __shared__ __align__(16) u16 Tr[128 * 130];

    const int g = blockIdx.z;
    const int n0 = blockIdx.y * 128, pl0 = blockIdx.x * 128;
    const int n1b = *n1b_p, n1p = *n1p_p;
    const int hh = (n0 >= n1b) ? 1 : 0;
    const int p0 = hh ? n1p : 0;
    const int Ph = hh ? (PT - n1p) : n1p;
    if (pl0 >= Ph) return;
    const int t = threadIdx.x;
    const int w = t >> 6, lane = t & 63;
    const int wm = w >> 1, wn = w & 1;
    const int lr = lane >> 3, lc = lane & 7, gch = lc ^ lr;
    const int fm = lane & 15, quad = lane >> 4;

    float4v zero4 = {0.f, 0.f, 0.f, 0.f};
    float4v acc[4][4];
#pragma unroll
    for (int i = 0; i < 4; ++i)
#pragma unroll
        for (int j = 0; j < 4; ++j) acc[i][j] = zero4;

#pragma unroll
    for (int i = 0; i < 4; ++i) {
        int row = w * 32 + i * 8 + lr;
        dma16(Qb + (size_t)(n0 + row) * 1024 + g * 64 + gch * 8,
              Qs + (w * 32 + i * 8) * 64 + lane * 8);
        dma16(Kb + (size_t)(p0 + pl0 + row) * 1024 + g * 64 + gch * 8,
              Ks + (w * 32 + i * 8) * 64 + lane * 8);
    }
    __syncthreads();
#pragma unroll
    for (int ks = 0; ks < 2; ++ks) {
        int c = ks * 4 + quad;
        short8 af[4], bf[4];
#pragma unroll
        for (int i = 0; i < 4; ++i) {
            int ra = wm * 64 + i * 16 + fm;
            af[i] = *(const short8*)(Qs + ra * 64 + ((c ^ (ra & 7)) * 8));
            int rb = wn * 64 + i * 16 + fm;
            bf[i] = *(const short8*)(Ks + rb * 64 + ((c ^ (rb & 7)) * 8));
        }
#pragma unroll
        for (int i = 0; i < 4; ++i)
#pragma unroll
            for (int j = 0; j < 4; ++j)
                acc[i][j] = __builtin_amdgcn_mfma_f32_16x16x32_bf16(af[i], bf[j], acc[i][j], 0, 0, 0);
    }
#pragma unroll
    for (int j = 0; j < 4; ++j) {
        int pl = wn * 64 + j * 16 + fm;
#pragma unroll
        for (int i = 0; i < 4; ++i)
#pragma unroll
            for (int r = 0; r < 4; ++r) {
                int nl = wm * 64 + i * 16 + quad * 4 + r;
                Tr[nl * 130 + pl] = f2bf(__expf(acc[i][j][r] * 0.0625f));
            }
    }
    __syncthreads();
#pragma unroll
    for (int i = 0; i < 8; ++i) {
        int f = i * 2048 + t * 8;
        int nl = f >> 7, pl = f & 127;
        short8 v = *(const short8*)(Tr + nl * 130 + pl);
        *(short8*)(ATT + ((size_t)(n0 + nl) * 16 + g) * 1024 + pl0 + pl) = v;
    }
}

// ---------------------------------------------------------------------------
// softmax: w[n,g,p] = max(pf,1e-6)*eatt, UNNORMALIZED, in-place in ATT (direct
// global RMW in D-layout). Software-pipelined: PD + eatt prefetched one tile
// ahead. INV[n][g] = 1/sum_p w.
// ---------------------------------------------------------------------------
__global__ __launch_bounds__(256)
void softmax_fused(const float* __restrict__ rois, const float4* __restrict__ PD,
                   const float* __restrict__ Wg_w, const float* __restrict__ Wg_b,
                   u16* __restrict__ ATT, float* __restrict__ INV,
                   const int* __restrict__ n1b_p, const int* __restrict__ n1p_p, int PT) {
    __shared__ float redl[4][16];

    const int n = blockIdx.x, t = threadIdx.x;
    const int w = t >> 6, lane = t & 63;
    const int fm = lane & 15, quad = lane >> 4;
    const int n1b = *n1b_p, n1p = *n1p_p;
    const int hh = (n >= n1b) ? 1 : 0;
    const int p0 = hh ? n1p : 0;
    const int Ph = hh ? (PT - n1p) : n1p;   // 1024

    // n-box (block-uniform)
    float xmin = rois[n * 5 + 1], ymin = rois[n * 5 + 2];
    float xmax = rois[n * 5 + 3], ymax = rois[n * 5 + 4];
    float bw = xmax - xmin + 1.0f, bh = ymax - ymin + 1.0f;
    float cx = 0.5f * (xmin + xmax), cy = 0.5f * (ymin + ymax);

    const int jA = quad >> 1, trig = quad & 1;
    float cA   = (jA == 0) ? cx : cy;
    float invA = (jA == 0) ? (1.0f / bw) : (1.0f / bh);
    float lB   = (jA == 0) ? __logf(bw) : __logf(bh);
    float toff = trig ? 0.25f : 0.0f;

    // Wg b-fragments in registers; bias folded into acc init
    const int g_ = fm;
    short8 b1, b2;
    {
        const float* w1 = Wg_w + g_ * 64 + quad * 8;
        const float* w2 = Wg_w + g_ * 64 + 32 + quad * 8;
        unsigned* p1 = (unsigned*)&b1;
        unsigned* p2 = (unsigned*)&b2;
#pragma unroll
        for (int kk = 0; kk < 4; ++kk) {
            p1[kk] = pkbf(w1[2 * kk], w1[2 * kk + 1]);
            p2[kk] = pkbf(w2[2 * kk], w2[2 * kk + 1]);
        }
    }
    float wgb = Wg_b[g_];

    const float inv_em[8] = {1.0f, 0.4216965034f, 0.1778279410f, 0.0749894209f,
                             0.0316227766f, 0.0133352143f, 0.0056234133f, 0.0023713737f};
    const float REV = 15.91549431f;  // 100 / (2*pi)
    const int prange = Ph >> 2;      // p per wave (256)
    const int pb0 = w * prange;
    float ssum = 0.0f;
    u16* rowp = ATT + ((size_t)n * 16 + g_) * 1024;  // row for g = fm

    // software pipeline: prefetch PD + eatt one tile ahead
    float4 pd_c = PD[p0 + pb0 + fm];
    ushort4 ea_c = *(const ushort4*)(rowp + pb0 + quad * 4);

#pragma unroll 2
    for (int pt = 0; pt < 16; ++pt) {
        int pbase = pb0 + pt * 16;
        float4 pd_n;
        ushort4 ea_n;
        if (pt < 15) {
            pd_n = PD[p0 + pbase + 16 + fm];
            ea_n = *(const ushort4*)(rowp + pbase + 16 + quad * 4);
        }
        float pc = (jA == 0) ? pd_c.x : pd_c.y;
        float lp = (jA == 0) ? pd_c.z : pd_c.w;
        float posA = __logf(fmaxf(fabsf(cA - pc) * invA, 0.001f));
        float posB = lp - lB;
        float br1 = posA * REV, br2 = posB * REV;
        float e1[8], e2[8];
#pragma unroll
        for (int k = 0; k < 8; ++k) {
            e1[k] = sin_rev(fmaf(br1, inv_em[k], toff));
            e2[k] = sin_rev(fmaf(br2, inv_em[k], toff));
        }
        short8 a1, a2;
        unsigned* pa1 = (unsigned*)&a1;
        unsigned* pa2 = (unsigned*)&a2;
#pragma unroll
        for (int kk = 0; kk < 4; ++kk) {
            pa1[kk] = pkbf(e1[2 * kk], e1[2 * kk + 1]);
            pa2[kk] = pkbf(e2[2 * kk], e2[2 * kk + 1]);
        }
        float4v acc = {wgb, wgb, wgb, wgb};
        acc = __builtin_amdgcn_mfma_f32_16x16x32_bf16(a1, b1, acc, 0, 0, 0);
        acc = __builtin_amdgcn_mfma_f32_16x16x32_bf16(a2, b2, acc, 0, 0, 0);

        float w0  = fmaxf(acc[0], 1e-6f) * bf2f(ea_c.x);
        float w1v = fmaxf(acc[1], 1e-6f) * bf2f(ea_c.y);
        float w2v = fmaxf(acc[2], 1e-6f) * bf2f(ea_c.z);
        float w3v = fmaxf(acc[3], 1e-6f) * bf2f(ea_c.w);
        ssum += (w0 + w1v) + (w2v + w3v);
        uint2 wp; wp.x = pkbf(w0, w1v); wp.y = pkbf(w2v, w3v);
        *(uint2*)(rowp + pbase + quad * 4) = wp;

        pd_c = pd_n;
        ea_c = ea_n;
    }

    ssum += __shfl_xor(ssum, 16, 64);
    ssum += __shfl_xor(ssum, 32, 64);
    if (lane < 16) redl[w][lane] = ssum;
    __syncthreads();
    if (t < 16)
        INV[(size_t)n * 16 + t] = 1.0f / (redl[0][t] + redl[1][t] + redl[2][t] + redl[3][t]);
}

// ---------------------------------------------------------------------------
// rel: OUT[n, g*64+o] = (sum_p w[n,g,p]*PVt[g*64+o, p0+p]) * INV[n,g] + conv_b
// Tile 64n x 64o, grid (NT/64, 16) = 512 blocks (2/CU).
// ---------------------------------------------------------------------------
__global__ __launch_bounds__(256)
void rel_mfma(const u16* __restrict__ SM, const u16* __restrict__ PVt,
              const float* __restrict__ conv_b, const float* __restrict__ INV,
              float* __restrict__ OUT, const int* __restrict__ n1b_p,
              const int* __restrict__ n1p_p, int PT) {
    __shared__ __align__(16) u16 As[64 * 64];
    __shared__ __align__(16) u16 Bs[64 * 64];

    const int n0 = blockIdx.x * 64, g = blockIdx.y;
    const int n1b = *n1b_p, n1p = *n1p_p;
    const int hh = (n0 >= n1b) ? 1 : 0;
    const int p0 = hh ? n1p : 0;
    const int Ph = hh ? (PT - n1p) : n1p;
    const int t = threadIdx.x;
    const int w = t >> 6, lane = t & 63;
    const int wm = w >> 1, wn = w & 1;
    const int lr = lane >> 3, lc = lane & 7, gch = lc ^ lr;
    const int fm = lane & 15, quad = lane >> 4;

    float4v zero4 = {0.f, 0.f, 0.f, 0.f};
    float4v acc[2][2];
#pragma unroll
    for (int i = 0; i < 2; ++i) { acc[i][0] = zero4; acc[i][1] = zero4; }

    for (int k0 = 0; k0 < Ph; k0 += 64) {
#pragma unroll
        for (int i = 0; i < 2; ++i) {
            int row = w * 16 + i * 8 + lr;
            dma16(SM + ((size_t)(n0 + row) * 16 + g) * 1024 + k0 + gch * 8,
                  As + (w * 16 + i * 8) * 64 + lane * 8);
            dma16(PVt + (size_t)(g * 64 + row) * PT + p0 + k0 + gch * 8,
                  Bs + (w * 16 + i * 8) * 64 + lane * 8);
        }
        __syncthreads();
#pragma unroll
        for (int ks = 0; ks < 2; ++ks) {
            int c = ks * 4 + quad;
            short8 af[2], bf[2];
#pragma unroll
            for (int i = 0; i < 2; ++i) {
                int ra = wm * 32 + i * 16 + fm;
                af[i] = *(const short8*)(As + ra * 64 + ((c ^ (ra & 7)) * 8));
                int rb = wn * 32 + i * 16 + fm;
                bf[i] = *(const short8*)(Bs + rb * 64 + ((c ^ (rb & 7)) * 8));
            }
#pragma unroll
            for (int i = 0; i < 2; ++i)
#pragma unroll
                for (int j = 0; j < 2; ++j)
                    acc[i][j] = __builtin_amdgcn_mfma_f32_16x16x32_bf16(af[i], bf[j], acc[i][j], 0, 0, 0);
        }
        __syncthreads();
    }
    float bb[2];
    bb[0] = conv_b[g * 64 + wn * 32 + fm];
    bb[1] = conv_b[g * 64 + wn * 32 + 16 + fm];
#pragma unroll
    for (int i = 0; i < 2; ++i)
#pragma unroll
        for (int r = 0; r < 4; ++r) {
            int nn = n0 + wm * 32 + i * 16 + quad * 4 + r;
            float iv = INV[(size_t)nn * 16 + g];
#pragma unroll
            for (int j = 0; j < 2; ++j) {
                int o = wn * 32 + j * 16 + fm;
                OUT[(size_t)nn * 1024 + g * 64 + o] = acc[i][j][r] * iv + bb[j];
            }
        }
}

extern "C" void kernel_launch(void* const* d_in, const int* in_sizes, int n_in,
                              void* d_out, int out_size, void* d_ws, size_t ws_size,
                              hipStream_t stream) {
    const float* rois   = (const float*)d_in[0];
    const float* prois  = (const float*)d_in[1];
    const float* bfeat  = (const float*)d_in[2];
    const float* pfeat  = (const float*)d_in[3];
    const float* Wg_w   = (const float*)d_in[4];
    const float* Wg_b   = (const float*)d_in[5];
    const float* Wq_w   = (const float*)d_in[6];
    const float* Wq_b   = (const float*)d_in[7];
    const float* Wk_w   = (const float*)d_in[8];
    const float* Wk_b   = (const float*)d_in[9];
    const float* conv_w = (const float*)d_in[10];
    const float* conv_b = (const float*)d_in[11];
    const int*   n1b    = (const int*)d_in[12];
    const int*   n1p    = (const int*)d_in[13];

    const int NT = in_sizes[2] / 1024;  // 2048
    const int PT = in_sizes[3] / 1024;  // 2048

    u16* ATT = (u16*)d_ws;                          // [NT][16][1024]
    u16* Qb  = ATT + (size_t)NT * 16 * 1024;        // [NT][1024]
    u16* Kb  = Qb + (size_t)NT * 1024;              // [PT][1024]
    u16* PVt = Kb + (size_t)PT * 1024;              // [1024][PT]
    float* INVp = (float*)(PVt + (size_t)1024 * PT);   // [NT][16]
    float4* PD  = (float4*)(INVp + (size_t)NT * 16);   // [PT]
    u16* Ab  = ATT;                                 // aliases (consumed by proj)
    u16* Pb  = Ab + (size_t)NT * 1024;
    u16* Wqb = Pb + (size_t)PT * 1024;
    u16* Wkb = Wqb + 1024 * 1024;
    u16* Cwb = Wkb + 1024 * 1024;

    dim3 blk(256);
    int nf4 = NT * 1024 / 4, pf4 = PT * 1024 / 4, wf4 = 1024 * 1024 / 4;
    int tot = nf4 + pf4 + 3 * wf4 + PT;
    cvt_all<<<dim3((tot + 255) / 256), blk, 0, stream>>>(
        bfeat, pfeat, Wq_w, Wk_w, conv_w, prois, Ab, Pb, Wqb, Wkb, Cwb, PD,
        nf4, pf4, wf4, PT);

    proj_mfma<<<dim3(16, NT / 128, 3), blk, 0, stream>>>(Ab, Pb, Wqb, Wkb, Cwb,
                                                         Wq_b, Wk_b, Qb, Kb, PVt, PT);
    att_mfma<<<dim3(PT / 128, NT / 128, 16), blk, 0, stream>>>(Qb, Kb, ATT, n1b, n1p, PT);
    softmax_fused<<<dim3(NT), blk, 0, stream>>>(rois, PD, Wg_w, Wg_b, ATT, INVp, n1b, n1p, PT);
    rel_mfma<<<dim3(NT / 64, 16), blk, 0, stream>>>(ATT, PVt, conv_b, INVp,
                                                    (float*)d_out, n1b, n1p, PT);
}